// Round 1
// baseline (3297.632 us; speedup 1.0000x reference)
//
#include <hip/hip_runtime.h>
#include <cstddef>
#include <cstdint>

// Problem: B=8, S=2048, IN=64, H=128, OUT=64. All fp32.
// out = [8,2048,64] (1,048,576) ++ hn [1,8,128] (1024) ++ cn [1,8,128] (1024)

__device__ __forceinline__ float fsig(float x) { return 1.0f / (1.0f + __expf(-x)); }
__device__ __forceinline__ float ftanh(float x) { return 1.0f - 2.0f / (__expf(2.0f * x) + 1.0f); }

// ---------------------------------------------------------------------------
// Kernel 1: x_proj[b,s,g] = sum_k x[b,s,k]*W_ih[g,k] + (b_ih[g]+b_hh[g])
// grid 2048 blocks x 256 thr; each block does 8 rows (of 16384) x 512 gates.
// ---------------------------------------------------------------------------
__global__ __launch_bounds__(256) void xproj_kernel(
    const float* __restrict__ x, const float* __restrict__ W_ih,
    const float* __restrict__ b_ih, const float* __restrict__ b_hh,
    float* __restrict__ xproj)
{
    __shared__ __align__(16) float xs[8][64];
    const int t = threadIdx.x;
    const long row0 = (long)blockIdx.x * 8;

    if (t < 128) {
        int r = t >> 4, c4 = (t & 15) * 4;
        *(float4*)&xs[r][c4] = *(const float4*)&x[(row0 + r) * 64 + c4];
    }
    __syncthreads();

    const int g0 = t, g1 = t + 256;
    float acc0[8], acc1[8];
#pragma unroll
    for (int r = 0; r < 8; ++r) { acc0[r] = 0.f; acc1[r] = 0.f; }

#pragma unroll
    for (int c = 0; c < 16; ++c) {
        float4 w0 = *(const float4*)&W_ih[g0 * 64 + c * 4];
        float4 w1 = *(const float4*)&W_ih[g1 * 64 + c * 4];
#pragma unroll
        for (int r = 0; r < 8; ++r) {
            float4 xv = *(const float4*)&xs[r][c * 4];
            acc0[r] += w0.x * xv.x + w0.y * xv.y + w0.z * xv.z + w0.w * xv.w;
            acc1[r] += w1.x * xv.x + w1.y * xv.y + w1.z * xv.z + w1.w * xv.w;
        }
    }
    const float bb0 = b_ih[g0] + b_hh[g0];
    const float bb1 = b_ih[g1] + b_hh[g1];
#pragma unroll
    for (int r = 0; r < 8; ++r) {
        xproj[(row0 + r) * 512 + g0] = acc0[r] + bb0;
        xproj[(row0 + r) * 512 + g1] = acc1[r] + bb1;
    }
}

// ---------------------------------------------------------------------------
// Kernel 2: sequential LSTM. One block per batch (8 blocks), 512 threads.
// Thread g holds W_hh row g (128 fp32) in VGPRs; h broadcast via LDS.
// ---------------------------------------------------------------------------
__global__ __launch_bounds__(512, 2) void lstm_kernel(
    const float* __restrict__ xproj, const float* __restrict__ W_hh,
    const float* __restrict__ h0, const float* __restrict__ c0,
    float* __restrict__ ys, float* __restrict__ hn, float* __restrict__ cn)
{
    const int b = blockIdx.x;   // 0..7
    const int t = threadIdx.x;  // 0..511
    __shared__ __align__(16) float h_lds[128];
    __shared__ __align__(16) float gate_lds[512];

    float4 w[32];
#pragma unroll
    for (int c = 0; c < 32; ++c) w[c] = *(const float4*)&W_hh[t * 128 + c * 4];

    float c_reg = 0.f;
    if (t < 128) { h_lds[t] = h0[b * 128 + t]; c_reg = c0[b * 128 + t]; }
    __syncthreads();

    const float* xp_base = xproj + (size_t)b * 2048 * 512 + t;
    float* ys_base = ys + (size_t)b * 2048 * 128;

    for (int step = 0; step < 2048; ++step) {
        float xp = xp_base[(size_t)step * 512];
        float a0 = 0.f, a1 = 0.f, a2 = 0.f, a3 = 0.f;
#pragma unroll
        for (int c = 0; c < 32; ++c) {
            float4 h4 = *(const float4*)&h_lds[c * 4];
            a0 += w[c].x * h4.x;
            a1 += w[c].y * h4.y;
            a2 += w[c].z * h4.z;
            a3 += w[c].w * h4.w;
        }
        gate_lds[t] = ((a0 + a1) + (a2 + a3)) + xp;
        __syncthreads();
        if (t < 128) {
            float gi = gate_lds[t], gf = gate_lds[128 + t];
            float gg = gate_lds[256 + t], go = gate_lds[384 + t];
            float i_ = fsig(gi), f_ = fsig(gf), g_ = ftanh(gg), o_ = fsig(go);
            c_reg = f_ * c_reg + i_ * g_;
            float h = o_ * ftanh(c_reg);
            h_lds[t] = h;
            ys_base[(size_t)step * 128 + t] = h;
        }
        __syncthreads();
    }
    if (t < 128) { hn[b * 128 + t] = h_lds[t]; cn[b * 128 + t] = c_reg; }
}

// ---------------------------------------------------------------------------
// Kernel 3: fused flash attention (Q=K=V=ys, unscaled) + residual + fc.
// grid (32 q-tiles, 8 batches), 256 threads (16x16), q-tile=64, kv-tile=64.
// Per-thread 4x4 score tile; online softmax; PV accumulate; epilogue fc.
// LDS: Qs 64x128 | KVs 64x128 | Ps 64x68  => 82,944 B dynamic.
// ---------------------------------------------------------------------------
__global__ __launch_bounds__(256) void attn_kernel(
    const float* __restrict__ ys, const float* __restrict__ fc_w,
    const float* __restrict__ fc_b, float* __restrict__ out)
{
    extern __shared__ float sm[];
    float* Qs = sm;             // 64*128
    float* KVs = sm + 64 * 128; // 64*128
    float* Ps = sm + 2 * 64 * 128; // 64*68 (padded stride)

    const int b = blockIdx.y, qt = blockIdx.x;
    const int t = threadIdx.x;
    const int tr = t >> 4, tc = t & 15;
    const float* Yb = ys + (size_t)b * 2048 * 128;

    // load Q tile (64x128): 8 float4 per thread
#pragma unroll
    for (int i = 0; i < 8; ++i) {
        int idx = t + i * 256;
        int r = idx >> 5, c = (idx & 31) * 4;
        *(float4*)&Qs[r * 128 + c] = *(const float4*)&Yb[((size_t)qt * 64 + r) * 128 + c];
    }

    float m_i[4], l_i[4], o_acc[4][8];
#pragma unroll
    for (int i = 0; i < 4; ++i) {
        m_i[i] = -1e30f; l_i[i] = 0.f;
#pragma unroll
        for (int j = 0; j < 8; ++j) o_acc[i][j] = 0.f;
    }

    for (int kt = 0; kt < 32; ++kt) {
        __syncthreads();  // previous PV (and Q load on first iter) done
        // stage KV tile
#pragma unroll
        for (int i = 0; i < 8; ++i) {
            int idx = t + i * 256;
            int r = idx >> 5, c = (idx & 31) * 4;
            *(float4*)&KVs[r * 128 + c] = *(const float4*)&Yb[((size_t)kt * 64 + r) * 128 + c];
        }
        __syncthreads();

        // ---- S = Q K^T (4x4 per thread), chunk-rotated by tc for bank spread
        float s[4][4];
#pragma unroll
        for (int i = 0; i < 4; ++i)
#pragma unroll
            for (int j = 0; j < 4; ++j) s[i][j] = 0.f;

#pragma unroll 8
        for (int c = 0; c < 32; ++c) {
            int cc4 = ((c + tc) & 31) << 2;
            float4 q[4], k[4];
#pragma unroll
            for (int i = 0; i < 4; ++i) q[i] = *(const float4*)&Qs[(tr * 4 + i) * 128 + cc4];
#pragma unroll
            for (int j = 0; j < 4; ++j) k[j] = *(const float4*)&KVs[(tc * 4 + j) * 128 + cc4];
#pragma unroll
            for (int i = 0; i < 4; ++i)
#pragma unroll
                for (int j = 0; j < 4; ++j)
                    s[i][j] += q[i].x * k[j].x + q[i].y * k[j].y + q[i].z * k[j].z + q[i].w * k[j].w;
        }

        // ---- online softmax over the 16-lane (tc) groups
#pragma unroll
        for (int i = 0; i < 4; ++i) {
            float mx = fmaxf(fmaxf(s[i][0], s[i][1]), fmaxf(s[i][2], s[i][3]));
#pragma unroll
            for (int off = 1; off < 16; off <<= 1)
                mx = fmaxf(mx, __shfl_xor(mx, off));
            float mnew = fmaxf(m_i[i], mx);
            float scale = __expf(m_i[i] - mnew);
            m_i[i] = mnew;
            float4 p;
            p.x = __expf(s[i][0] - mnew);
            p.y = __expf(s[i][1] - mnew);
            p.z = __expf(s[i][2] - mnew);
            p.w = __expf(s[i][3] - mnew);
            float rs = p.x + p.y + p.z + p.w;
#pragma unroll
            for (int off = 1; off < 16; off <<= 1)
                rs += __shfl_xor(rs, off);
            l_i[i] = l_i[i] * scale + rs;
            *(float4*)&Ps[(tr * 4 + i) * 68 + tc * 4] = p;
#pragma unroll
            for (int d = 0; d < 8; ++d) o_acc[i][d] *= scale;
        }
        __syncthreads();

        // ---- O += P * V.  d-cols: tc*4 and 64+tc*4
#pragma unroll 4
        for (int k4 = 0; k4 < 16; ++k4) {
            float pl[4][4];
#pragma unroll
            for (int i = 0; i < 4; ++i) {
                float4 p = *(const float4*)&Ps[(tr * 4 + i) * 68 + k4 * 4];
                pl[i][0] = p.x; pl[i][1] = p.y; pl[i][2] = p.z; pl[i][3] = p.w;
            }
#pragma unroll
            for (int kk = 0; kk < 4; ++kk) {
                int k = k4 * 4 + kk;
                float4 v0 = *(const float4*)&KVs[k * 128 + tc * 4];
                float4 v1 = *(const float4*)&KVs[k * 128 + 64 + tc * 4];
#pragma unroll
                for (int i = 0; i < 4; ++i) {
                    float pv = pl[i][kk];
                    o_acc[i][0] += pv * v0.x; o_acc[i][1] += pv * v0.y;
                    o_acc[i][2] += pv * v0.z; o_acc[i][3] += pv * v0.w;
                    o_acc[i][4] += pv * v1.x; o_acc[i][5] += pv * v1.y;
                    o_acc[i][6] += pv * v1.z; o_acc[i][7] += pv * v1.w;
                }
            }
        }
    }

    // ---- epilogue: attn_out = Q + O/l  -> KVs; fc_w -> Qs; out = attn_out @ fc_w^T + b
    __syncthreads();  // all PV reads of KVs done
#pragma unroll
    for (int i = 0; i < 4; ++i) {
        float inv_l = 1.0f / l_i[i];
        int row = tr * 4 + i;
        float4 a0, a1;
        a0.x = Qs[row * 128 + tc * 4 + 0] + o_acc[i][0] * inv_l;
        a0.y = Qs[row * 128 + tc * 4 + 1] + o_acc[i][1] * inv_l;
        a0.z = Qs[row * 128 + tc * 4 + 2] + o_acc[i][2] * inv_l;
        a0.w = Qs[row * 128 + tc * 4 + 3] + o_acc[i][3] * inv_l;
        a1.x = Qs[row * 128 + 64 + tc * 4 + 0] + o_acc[i][4] * inv_l;
        a1.y = Qs[row * 128 + 64 + tc * 4 + 1] + o_acc[i][5] * inv_l;
        a1.z = Qs[row * 128 + 64 + tc * 4 + 2] + o_acc[i][6] * inv_l;
        a1.w = Qs[row * 128 + 64 + tc * 4 + 3] + o_acc[i][7] * inv_l;
        *(float4*)&KVs[row * 128 + tc * 4] = a0;
        *(float4*)&KVs[row * 128 + 64 + tc * 4] = a1;
    }
    __syncthreads();  // attn_out staged; Qs reads done
#pragma unroll
    for (int i = 0; i < 8; ++i) {
        int idx = t + i * 256;
        int r = idx >> 5, c = (idx & 31) * 4;
        *(float4*)&Qs[r * 128 + c] = *(const float4*)&fc_w[r * 128 + c];
    }
    __syncthreads();

    float accf[4][4];
#pragma unroll
    for (int i = 0; i < 4; ++i)
#pragma unroll
        for (int j = 0; j < 4; ++j) accf[i][j] = 0.f;
#pragma unroll 8
    for (int c = 0; c < 32; ++c) {
        int cc4 = ((c + tc) & 31) << 2;
        float4 a[4], w[4];
#pragma unroll
        for (int i = 0; i < 4; ++i) a[i] = *(const float4*)&KVs[(tr * 4 + i) * 128 + cc4];
#pragma unroll
        for (int j = 0; j < 4; ++j) w[j] = *(const float4*)&Qs[(tc * 4 + j) * 128 + cc4];
#pragma unroll
        for (int i = 0; i < 4; ++i)
#pragma unroll
            for (int j = 0; j < 4; ++j)
                accf[i][j] += a[i].x * w[j].x + a[i].y * w[j].y + a[i].z * w[j].z + a[i].w * w[j].w;
    }

    float bj0 = fc_b[tc * 4 + 0], bj1 = fc_b[tc * 4 + 1];
    float bj2 = fc_b[tc * 4 + 2], bj3 = fc_b[tc * 4 + 3];
#pragma unroll
    for (int i = 0; i < 4; ++i) {
        float4 r;
        r.x = accf[i][0] + bj0; r.y = accf[i][1] + bj1;
        r.z = accf[i][2] + bj2; r.w = accf[i][3] + bj3;
        *(float4*)&out[((size_t)b * 2048 + (size_t)qt * 64 + tr * 4 + i) * 64 + tc * 4] = r;
    }
}

// ---------------------------------------------------------------------------
extern "C" void kernel_launch(void* const* d_in, const int* in_sizes, int n_in,
                              void* d_out, int out_size, void* d_ws, size_t ws_size,
                              hipStream_t stream) {
    const float* x   = (const float*)d_in[0];
    const float* h0  = (const float*)d_in[1];
    const float* c0  = (const float*)d_in[2];
    const float* Wih = (const float*)d_in[3];
    const float* Whh = (const float*)d_in[4];
    const float* bih = (const float*)d_in[5];
    const float* bhh = (const float*)d_in[6];
    const float* fcw = (const float*)d_in[7];
    const float* fcb = (const float*)d_in[8];
    (void)in_sizes; (void)n_in; (void)out_size; (void)ws_size;

    float* out = (float*)d_out;
    float* hn = out + (size_t)8 * 2048 * 64;
    float* cn = hn + 1024;

    float* xproj = (float*)d_ws;                       // 8*2048*512 fp32 = 32 MB
    float* ys    = xproj + (size_t)8 * 2048 * 512;     // 8*2048*128 fp32 = 8 MB

    xproj_kernel<<<2048, 256, 0, stream>>>(x, Wih, bih, bhh, xproj);
    lstm_kernel<<<8, 512, 0, stream>>>(xproj, Whh, h0, c0, ys, hn, cn);
    dim3 grid_attn(32, 8);
    attn_kernel<<<grid_attn, 256, 82944, stream>>>(ys, fcw, fcb, out);
}

// Round 2
// 2325.051 us; speedup vs baseline: 1.4183x; 1.4183x over previous
//
#include <hip/hip_runtime.h>
#include <cstddef>
#include <cstdint>

// Problem: B=8, S=2048, IN=64, H=128, OUT=64. All fp32.
// out = [8,2048,64] (1,048,576) ++ hn [1,8,128] (1024) ++ cn [1,8,128] (1024)

using short8 = __attribute__((ext_vector_type(8))) short;
using f32x4  = __attribute__((ext_vector_type(4))) float;

__device__ __forceinline__ float fsig(float x) { return 1.0f / (1.0f + __expf(-x)); }
__device__ __forceinline__ float ftanh(float x) { return 1.0f - 2.0f / (__expf(2.0f * x) + 1.0f); }

__device__ __forceinline__ ushort bf16_rne(float f) {
    uint u = __float_as_uint(f);
    return (ushort)((u + 0x7fffu + ((u >> 16) & 1u)) >> 16);
}
__device__ __forceinline__ float bf16_to_f(ushort h) {
    return __uint_as_float(((uint)h) << 16);
}

// ---------------------------------------------------------------------------
// Kernel 1: x_proj, stored INTERLEAVED: xp2[((b*2048+s)*128 + cell)*4 + part]
// part 0..3 = i,f,g,o gate pre-activations for that cell (biases included).
// ---------------------------------------------------------------------------
__global__ __launch_bounds__(256) void xproj_kernel(
    const float* __restrict__ x, const float* __restrict__ W_ih,
    const float* __restrict__ b_ih, const float* __restrict__ b_hh,
    float* __restrict__ xp2)
{
    __shared__ __align__(16) float xs[8][64];
    const int t = threadIdx.x;
    const long row0 = (long)blockIdx.x * 8;

    if (t < 128) {
        int r = t >> 4, c4 = (t & 15) * 4;
        *(float4*)&xs[r][c4] = *(const float4*)&x[(row0 + r) * 64 + c4];
    }
    __syncthreads();

    const int g0 = t, g1 = t + 256;
    float acc0[8], acc1[8];
#pragma unroll
    for (int r = 0; r < 8; ++r) { acc0[r] = 0.f; acc1[r] = 0.f; }

#pragma unroll
    for (int c = 0; c < 16; ++c) {
        float4 w0 = *(const float4*)&W_ih[g0 * 64 + c * 4];
        float4 w1 = *(const float4*)&W_ih[g1 * 64 + c * 4];
#pragma unroll
        for (int r = 0; r < 8; ++r) {
            float4 xv = *(const float4*)&xs[r][c * 4];
            acc0[r] += w0.x * xv.x + w0.y * xv.y + w0.z * xv.z + w0.w * xv.w;
            acc1[r] += w1.x * xv.x + w1.y * xv.y + w1.z * xv.z + w1.w * xv.w;
        }
    }
    const float bb0 = b_ih[g0] + b_hh[g0];
    const float bb1 = b_ih[g1] + b_hh[g1];
    const int c0i = g0 & 127, p0 = g0 >> 7;
    const int c1i = g1 & 127, p1 = g1 >> 7;
#pragma unroll
    for (int r = 0; r < 8; ++r) {
        xp2[((row0 + r) * 128 + c0i) * 4 + p0] = acc0[r] + bb0;
        xp2[((row0 + r) * 128 + c1i) * 4 + p1] = acc1[r] + bb1;
    }
}

// ---------------------------------------------------------------------------
// Kernel 2: MFMA LSTM. One block per batch (8 blocks), 512 threads (8 waves).
//
// Per step: gates[512] = W_hh @ h via mfma_f32_16x16x32_bf16 with
//   A (16x32 tile) rows: row0=h_hi(bf16), row1=h_lo(bf16), rows 2..15 = 0
//   B = W_hh^T fragments, hi/lo bf16 split, resident in VGPRs (128/thread).
// gate = D_hi[row0] + D_hi[row1] + D_lo[row0]  (error ~2e-4/step, fp32-like)
// Wave w owns gate-tiles {w, w+8, w+16, w+24} = i,f,g,o for cells 16w..16w+15
// -> nonlinearity is wave-local in lanes 0..15, no cross-wave gate traffic.
// A-fragments double-buffered in LDS (frag-linear layout, shared k-bijection
// with the B packing so the HW k-mapping cancels). ONE barrier per step.
// ---------------------------------------------------------------------------
__global__ __launch_bounds__(512, 2) void lstm_kernel(
    const float* __restrict__ xp2, const float* __restrict__ W_hh,
    const float* __restrict__ h0, const float* __restrict__ c0,
    float* __restrict__ ys, float* __restrict__ hn, float* __restrict__ cn)
{
    const int b    = blockIdx.x;     // 0..7
    const int t    = threadIdx.x;    // 0..511
    const int w    = t >> 6;         // wave 0..7
    const int lane = t & 63;
    const int l16  = lane & 15;
    const int sub  = lane >> 4;      // 0..3

    // frag-linear A storage: [buf][ktile][lane][elem], 16B per lane per ktile
    __shared__ __align__(16) ushort afrag[2][4][64][8];   // 8 KB

    // ---- load + split W_hh fragments once; k-slot bijection:
    //      k(j,lane) = kt*32 + (j>>2)*16 + sub*4 + (j&3); 16-dim = l16 (gate col)
    short8 Bf[4][4][2];   // [gate-tile-idx][ktile][hi/lo]  = 128 VGPRs
#pragma unroll
    for (int gi = 0; gi < 4; ++gi) {
        const int gate = (w + 8 * gi) * 16 + l16;
#pragma unroll
        for (int kt = 0; kt < 4; ++kt) {
            short8 vhi, vlo;
#pragma unroll
            for (int j = 0; j < 8; ++j) {
                int k = kt * 32 + (j >> 2) * 16 + sub * 4 + (j & 3);
                float wv = W_hh[gate * 128 + k];
                ushort hb = bf16_rne(wv);
                ushort lb = bf16_rne(wv - bf16_to_f(hb));
                vhi[j] = (short)hb;
                vlo[j] = (short)lb;
            }
            Bf[gi][kt][0] = vhi;
            Bf[gi][kt][1] = vlo;
        }
    }

    // zero A-frag region (rows >=2 stay zero forever)
    ((uint4*)afrag)[t] = make_uint4(0u, 0u, 0u, 0u);   // 512*16B = 8KB

    const int cell = w * 16 + l16;   // meaningful for lanes 0..15
    float c_reg = 0.f, h_last = 0.f;

    if (lane < 16) {
        c_reg  = c0[b * 128 + cell];
        h_last = h0[b * 128 + cell];
        // write initial h fragment into buf 0
        int kt = cell >> 5, kl = cell & 31;
        int lidx = 16 * ((kl >> 2) & 3);
        int elem = (kl >> 4) * 4 + (kl & 3);
        ushort hb = bf16_rne(h_last);
        afrag[0][kt][lidx + 0][elem] = hb;
        afrag[0][kt][lidx + 1][elem] = bf16_rne(h_last - bf16_to_f(hb));
    }
    __syncthreads();

    const float* xpb = xp2 + (size_t)b * 2048 * 512;
    float* ysb = ys + (size_t)b * 2048 * 128;

    short8 az;
#pragma unroll
    for (int j = 0; j < 8; ++j) az[j] = 0;

    float4 xq = make_float4(0.f, 0.f, 0.f, 0.f);
    if (lane < 16) xq = *(const float4*)&xpb[(size_t)cell * 4];

    for (int s = 0; s < 2048; ++s) {
        const int rb = s & 1, wb = rb ^ 1;

        // prefetch next step's xproj (latency hidden under MFMAs)
        float4 xn = xq;
        if (lane < 16) {
            int sn = (s + 1 < 2048) ? s + 1 : s;
            xn = *(const float4*)&xpb[(size_t)sn * 512 + cell * 4];
        }

        // A fragments: only lanes with l16<2 carry data (rows 0/1)
        short8 A[4];
#pragma unroll
        for (int kt = 0; kt < 4; ++kt) {
            short8 av = az;
            if (l16 < 2) av = *(const short8*)&afrag[rb][kt][lane][0];
            A[kt] = av;
        }

        // 32 MFMAs: 4 gate-tiles x 4 k-tiles x {W_hi, W_lo}
        float gv[4];
#pragma unroll
        for (int gi = 0; gi < 4; ++gi) {
            f32x4 a1 = {0.f, 0.f, 0.f, 0.f};
            f32x4 a2 = {0.f, 0.f, 0.f, 0.f};
#pragma unroll
            for (int kt = 0; kt < 4; ++kt) {
                a1 = __builtin_amdgcn_mfma_f32_16x16x32_bf16(A[kt], Bf[gi][kt][0], a1, 0, 0, 0);
                a2 = __builtin_amdgcn_mfma_f32_16x16x32_bf16(A[kt], Bf[gi][kt][1], a2, 0, 0, 0);
            }
            gv[gi] = a1[0] + a1[1] + a2[0];
        }

        // wave-local nonlinearity on lanes 0..15 (cells 16w..16w+15)
        if (lane < 16) {
            float i_ = fsig(gv[0] + xq.x);
            float f_ = fsig(gv[1] + xq.y);
            float g_ = ftanh(gv[2] + xq.z);
            float o_ = fsig(gv[3] + xq.w);
            c_reg = f_ * c_reg + i_ * g_;
            float h = o_ * ftanh(c_reg);
            h_last = h;
            ysb[(size_t)s * 128 + cell] = h;

            int kt = cell >> 5, kl = cell & 31;
            int lidx = 16 * ((kl >> 2) & 3);
            int elem = (kl >> 4) * 4 + (kl & 3);
            ushort hb = bf16_rne(h);
            afrag[wb][kt][lidx + 0][elem] = hb;
            afrag[wb][kt][lidx + 1][elem] = bf16_rne(h - bf16_to_f(hb));
        }
        __syncthreads();
        xq = xn;
    }

    if (lane < 16) {
        hn[b * 128 + cell] = h_last;
        cn[b * 128 + cell] = c_reg;
    }
}

// ---------------------------------------------------------------------------
// Kernel 3: fused flash attention (Q=K=V=ys, unscaled) + residual + fc.
// (unchanged from round 0 -- becomes the top dispatch; next round's target)
// ---------------------------------------------------------------------------
__global__ __launch_bounds__(256) void attn_kernel(
    const float* __restrict__ ys, const float* __restrict__ fc_w,
    const float* __restrict__ fc_b, float* __restrict__ out)
{
    extern __shared__ float sm[];
    float* Qs = sm;                // 64*128
    float* KVs = sm + 64 * 128;    // 64*128
    float* Ps = sm + 2 * 64 * 128; // 64*68 (padded stride)

    const int b = blockIdx.y, qt = blockIdx.x;
    const int t = threadIdx.x;
    const int tr = t >> 4, tc = t & 15;
    const float* Yb = ys + (size_t)b * 2048 * 128;

#pragma unroll
    for (int i = 0; i < 8; ++i) {
        int idx = t + i * 256;
        int r = idx >> 5, c = (idx & 31) * 4;
        *(float4*)&Qs[r * 128 + c] = *(const float4*)&Yb[((size_t)qt * 64 + r) * 128 + c];
    }

    float m_i[4], l_i[4], o_acc[4][8];
#pragma unroll
    for (int i = 0; i < 4; ++i) {
        m_i[i] = -1e30f; l_i[i] = 0.f;
#pragma unroll
        for (int j = 0; j < 8; ++j) o_acc[i][j] = 0.f;
    }

    for (int kt = 0; kt < 32; ++kt) {
        __syncthreads();
#pragma unroll
        for (int i = 0; i < 8; ++i) {
            int idx = t + i * 256;
            int r = idx >> 5, c = (idx & 31) * 4;
            *(float4*)&KVs[r * 128 + c] = *(const float4*)&Yb[((size_t)kt * 64 + r) * 128 + c];
        }
        __syncthreads();

        float s[4][4];
#pragma unroll
        for (int i = 0; i < 4; ++i)
#pragma unroll
            for (int j = 0; j < 4; ++j) s[i][j] = 0.f;

#pragma unroll 8
        for (int c = 0; c < 32; ++c) {
            int cc4 = ((c + tc) & 31) << 2;
            float4 q[4], k[4];
#pragma unroll
            for (int i = 0; i < 4; ++i) q[i] = *(const float4*)&Qs[(tr * 4 + i) * 128 + cc4];
#pragma unroll
            for (int j = 0; j < 4; ++j) k[j] = *(const float4*)&KVs[(tc * 4 + j) * 128 + cc4];
#pragma unroll
            for (int i = 0; i < 4; ++i)
#pragma unroll
                for (int j = 0; j < 4; ++j)
                    s[i][j] += q[i].x * k[j].x + q[i].y * k[j].y + q[i].z * k[j].z + q[i].w * k[j].w;
        }

#pragma unroll
        for (int i = 0; i < 4; ++i) {
            float mx = fmaxf(fmaxf(s[i][0], s[i][1]), fmaxf(s[i][2], s[i][3]));
#pragma unroll
            for (int off = 1; off < 16; off <<= 1)
                mx = fmaxf(mx, __shfl_xor(mx, off));
            float mnew = fmaxf(m_i[i], mx);
            float scale = __expf(m_i[i] - mnew);
            m_i[i] = mnew;
            float4 p;
            p.x = __expf(s[i][0] - mnew);
            p.y = __expf(s[i][1] - mnew);
            p.z = __expf(s[i][2] - mnew);
            p.w = __expf(s[i][3] - mnew);
            float rs = p.x + p.y + p.z + p.w;
#pragma unroll
            for (int off = 1; off < 16; off <<= 1)
                rs += __shfl_xor(rs, off);
            l_i[i] = l_i[i] * scale + rs;
            *(float4*)&Ps[(tr * 4 + i) * 68 + tc * 4] = p;
#pragma unroll
            for (int d = 0; d < 8; ++d) o_acc[i][d] *= scale;
        }
        __syncthreads();

#pragma unroll 4
        for (int k4 = 0; k4 < 16; ++k4) {
            float pl[4][4];
#pragma unroll
            for (int i = 0; i < 4; ++i) {
                float4 p = *(const float4*)&Ps[(tr * 4 + i) * 68 + k4 * 4];
                pl[i][0] = p.x; pl[i][1] = p.y; pl[i][2] = p.z; pl[i][3] = p.w;
            }
#pragma unroll
            for (int kk = 0; kk < 4; ++kk) {
                int k = k4 * 4 + kk;
                float4 v0 = *(const float4*)&KVs[k * 128 + tc * 4];
                float4 v1 = *(const float4*)&KVs[k * 128 + 64 + tc * 4];
#pragma unroll
                for (int i = 0; i < 4; ++i) {
                    float pv = pl[i][kk];
                    o_acc[i][0] += pv * v0.x; o_acc[i][1] += pv * v0.y;
                    o_acc[i][2] += pv * v0.z; o_acc[i][3] += pv * v0.w;
                    o_acc[i][4] += pv * v1.x; o_acc[i][5] += pv * v1.y;
                    o_acc[i][6] += pv * v1.z; o_acc[i][7] += pv * v1.w;
                }
            }
        }
    }

    __syncthreads();
#pragma unroll
    for (int i = 0; i < 4; ++i) {
        float inv_l = 1.0f / l_i[i];
        int row = tr * 4 + i;
        float4 a0, a1;
        a0.x = Qs[row * 128 + tc * 4 + 0] + o_acc[i][0] * inv_l;
        a0.y = Qs[row * 128 + tc * 4 + 1] + o_acc[i][1] * inv_l;
        a0.z = Qs[row * 128 + tc * 4 + 2] + o_acc[i][2] * inv_l;
        a0.w = Qs[row * 128 + tc * 4 + 3] + o_acc[i][3] * inv_l;
        a1.x = Qs[row * 128 + 64 + tc * 4 + 0] + o_acc[i][4] * inv_l;
        a1.y = Qs[row * 128 + 64 + tc * 4 + 1] + o_acc[i][5] * inv_l;
        a1.z = Qs[row * 128 + 64 + tc * 4 + 2] + o_acc[i][6] * inv_l;
        a1.w = Qs[row * 128 + 64 + tc * 4 + 3] + o_acc[i][7] * inv_l;
        *(float4*)&KVs[row * 128 + tc * 4] = a0;
        *(float4*)&KVs[row * 128 + 64 + tc * 4] = a1;
    }
    __syncthreads();
#pragma unroll
    for (int i = 0; i < 8; ++i) {
        int idx = t + i * 256;
        int r = idx >> 5, c = (idx & 31) * 4;
        *(float4*)&Qs[r * 128 + c] = *(const float4*)&fc_w[r * 128 + c];
    }
    __syncthreads();

    float accf[4][4];
#pragma unroll
    for (int i = 0; i < 4; ++i)
#pragma unroll
        for (int j = 0; j < 4; ++j) accf[i][j] = 0.f;
#pragma unroll 8
    for (int c = 0; c < 32; ++c) {
        int cc4 = ((c + tc) & 31) << 2;
        float4 a[4], wv[4];
#pragma unroll
        for (int i = 0; i < 4; ++i) a[i] = *(const float4*)&KVs[(tr * 4 + i) * 128 + cc4];
#pragma unroll
        for (int j = 0; j < 4; ++j) wv[j] = *(const float4*)&Qs[(tc * 4 + j) * 128 + cc4];
#pragma unroll
        for (int i = 0; i < 4; ++i)
#pragma unroll
            for (int j = 0; j < 4; ++j)
                accf[i][j] += a[i].x * wv[j].x + a[i].y * wv[j].y + a[i].z * wv[j].z + a[i].w * wv[j].w;
    }

    float bj0 = fc_b[tc * 4 + 0], bj1 = fc_b[tc * 4 + 1];
    float bj2 = fc_b[tc * 4 + 2], bj3 = fc_b[tc * 4 + 3];
#pragma unroll
    for (int i = 0; i < 4; ++i) {
        float4 r;
        r.x = accf[i][0] + bj0; r.y = accf[i][1] + bj1;
        r.z = accf[i][2] + bj2; r.w = accf[i][3] + bj3;
        *(float4*)&out[((size_t)b * 2048 + (size_t)qt * 64 + tr * 4 + i) * 64 + tc * 4] = r;
    }
}

// ---------------------------------------------------------------------------
extern "C" void kernel_launch(void* const* d_in, const int* in_sizes, int n_in,
                              void* d_out, int out_size, void* d_ws, size_t ws_size,
                              hipStream_t stream) {
    const float* x   = (const float*)d_in[0];
    const float* h0  = (const float*)d_in[1];
    const float* c0  = (const float*)d_in[2];
    const float* Wih = (const float*)d_in[3];
    const float* Whh = (const float*)d_in[4];
    const float* bih = (const float*)d_in[5];
    const float* bhh = (const float*)d_in[6];
    const float* fcw = (const float*)d_in[7];
    const float* fcb = (const float*)d_in[8];
    (void)in_sizes; (void)n_in; (void)out_size; (void)ws_size;

    float* out = (float*)d_out;
    float* hn = out + (size_t)8 * 2048 * 64;
    float* cn = hn + 1024;

    float* xp2 = (float*)d_ws;                       // 8*2048*512 fp32 = 32 MB
    float* ys  = xp2 + (size_t)8 * 2048 * 512;       // 8*2048*128 fp32 = 8 MB

    xproj_kernel<<<2048, 256, 0, stream>>>(x, Wih, bih, bhh, xp2);
    lstm_kernel<<<8, 512, 0, stream>>>(xp2, Whh, h0, c0, ys, hn, cn);
    dim3 grid_attn(32, 8);
    attn_kernel<<<grid_attn, 256, 82944, stream>>>(ys, fcw, fcb, out);
}

// Round 3
// 1894.052 us; speedup vs baseline: 1.7410x; 1.2276x over previous
//
#include <hip/hip_runtime.h>
#include <cstddef>
#include <cstdint>

// Problem: B=8, S=2048, IN=64, H=128, OUT=64. All fp32.
// out = [8,2048,64] (1,048,576) ++ hn [1,8,128] (1024) ++ cn [1,8,128] (1024)

using short8 = __attribute__((ext_vector_type(8))) short;
using half8  = __attribute__((ext_vector_type(8))) _Float16;
using f32x4  = __attribute__((ext_vector_type(4))) float;

__device__ __forceinline__ float fsig(float x) { return 1.0f / (1.0f + __expf(-x)); }
__device__ __forceinline__ float ftanh(float x) { return 1.0f - 2.0f / (__expf(2.0f * x) + 1.0f); }

// ---------------------------------------------------------------------------
// Kernel 1: x_proj, stored INTERLEAVED: xp2[((b*2048+s)*128 + cell)*4 + part]
// part 0..3 = i,f,g,o gate pre-activations for that cell (biases included).
// ---------------------------------------------------------------------------
__global__ __launch_bounds__(256) void xproj_kernel(
    const float* __restrict__ x, const float* __restrict__ W_ih,
    const float* __restrict__ b_ih, const float* __restrict__ b_hh,
    float* __restrict__ xp2)
{
    __shared__ __align__(16) float xs[8][64];
    const int t = threadIdx.x;
    const long row0 = (long)blockIdx.x * 8;

    if (t < 128) {
        int r = t >> 4, c4 = (t & 15) * 4;
        *(float4*)&xs[r][c4] = *(const float4*)&x[(row0 + r) * 64 + c4];
    }
    __syncthreads();

    const int g0 = t, g1 = t + 256;
    float acc0[8], acc1[8];
#pragma unroll
    for (int r = 0; r < 8; ++r) { acc0[r] = 0.f; acc1[r] = 0.f; }

#pragma unroll
    for (int c = 0; c < 16; ++c) {
        float4 w0 = *(const float4*)&W_ih[g0 * 64 + c * 4];
        float4 w1 = *(const float4*)&W_ih[g1 * 64 + c * 4];
#pragma unroll
        for (int r = 0; r < 8; ++r) {
            float4 xv = *(const float4*)&xs[r][c * 4];
            acc0[r] += w0.x * xv.x + w0.y * xv.y + w0.z * xv.z + w0.w * xv.w;
            acc1[r] += w1.x * xv.x + w1.y * xv.y + w1.z * xv.z + w1.w * xv.w;
        }
    }
    const float bb0 = b_ih[g0] + b_hh[g0];
    const float bb1 = b_ih[g1] + b_hh[g1];
    const int c0i = g0 & 127, p0 = g0 >> 7;
    const int c1i = g1 & 127, p1 = g1 >> 7;
#pragma unroll
    for (int r = 0; r < 8; ++r) {
        xp2[((row0 + r) * 128 + c0i) * 4 + p0] = acc0[r] + bb0;
        xp2[((row0 + r) * 128 + c1i) * 4 + p1] = acc1[r] + bb1;
    }
}

// ---------------------------------------------------------------------------
// Kernel 2: MFMA LSTM, fp16 weights (single B), h split hi/lo fp16 in A rows
// 0/1 (Dekker compensation rides free in the same MFMA).
// One block per batch (8 blocks), 512 threads (8 waves).
// Per wave per step: 4 gate-tiles x 4 k-tiles = 16 mfma_f32_16x16x32_f16.
// Raw s_barrier + lgkmcnt(0) only (NO vmcnt drain): xproj prefetch (depth 2)
// and ys stores float across the barrier. Cross-wave traffic is LDS-only.
// ---------------------------------------------------------------------------
__global__ __launch_bounds__(512, 2) void lstm_kernel(
    const float* __restrict__ xp2, const float* __restrict__ W_hh,
    const float* __restrict__ h0, const float* __restrict__ c0,
    float* __restrict__ ys, float* __restrict__ hn, float* __restrict__ cn)
{
    const int b    = blockIdx.x;     // 0..7
    const int t    = threadIdx.x;    // 0..511
    const int w    = t >> 6;         // wave 0..7
    const int lane = t & 63;
    const int l16  = lane & 15;
    const int sub  = lane >> 4;      // 0..3

    // A-fragment store: [buf][ktile][slot][elem] fp16; slot = sub*2 + row(0/1)
    // 1 KB total; read by lanes with l16<2 at slot sub*2+l16 -> conflict-free.
    __shared__ __align__(16) _Float16 afrag[2][4][8][8];

    // ---- pack W_hh fragments once (fp16, single precision level).
    // shared k-bijection with A: k = kt*32 + (j>>2)*16 + sub*4 + (j&3)
    half8 Bf[4][4];   // [gate-tile][ktile] = 64 VGPRs
#pragma unroll
    for (int gi = 0; gi < 4; ++gi) {
        const int gate = (w + 8 * gi) * 16 + l16;
#pragma unroll
        for (int kt = 0; kt < 4; ++kt) {
            half8 v;
#pragma unroll
            for (int j = 0; j < 8; ++j) {
                int k = kt * 32 + (j >> 2) * 16 + sub * 4 + (j & 3);
                v[j] = (_Float16)W_hh[gate * 128 + k];
            }
            Bf[gi][kt] = v;
        }
    }

    const int cell = w * 16 + l16;   // meaningful for lanes 0..15
    float c_reg = 0.f, h_last = 0.f;

    if (lane < 16) {
        c_reg  = c0[b * 128 + cell];
        h_last = h0[b * 128 + cell];
        int kt = cell >> 5, kl = cell & 31;
        int slot = ((kl >> 2) & 3) * 2;
        int elem = (kl >> 4) * 4 + (kl & 3);
        _Float16 hh = (_Float16)h_last;
        afrag[0][kt][slot + 0][elem] = hh;
        afrag[0][kt][slot + 1][elem] = (_Float16)(h_last - (float)hh);
    }
    __syncthreads();   // one full barrier before steady state is fine

    const float* xpb = xp2 + (size_t)b * 2048 * 512;
    float* ysb = ys + (size_t)b * 2048 * 128;

    half8 az;
#pragma unroll
    for (int j = 0; j < 8; ++j) az[j] = (_Float16)0.f;

    // depth-2 xproj prefetch pipeline (covers ~2 steps of HBM latency)
    float4 xq0 = make_float4(0.f, 0.f, 0.f, 0.f);
    float4 xq1 = xq0;
    if (lane < 16) {
        xq0 = *(const float4*)&xpb[(size_t)cell * 4];
        xq1 = *(const float4*)&xpb[(size_t)512 + cell * 4];
    }

    for (int s = 0; s < 2048; ++s) {
        const int rb = s & 1, wb = rb ^ 1;

        // prefetch step s+2
        float4 xn = xq1;
        if (lane < 16 && s + 2 < 2048)
            xn = *(const float4*)&xpb[(size_t)(s + 2) * 512 + cell * 4];

        // A fragments: lanes l16<2 carry rows 0 (h_hi) / 1 (h_lo)
        half8 A[4];
#pragma unroll
        for (int kt = 0; kt < 4; ++kt) {
            half8 av = az;
            if (l16 < 2) av = *(const half8*)&afrag[rb][kt][sub * 2 + l16][0];
            A[kt] = av;
        }

        // 16 MFMAs: 4 gate-tiles x 4 k-tiles, single fp16 W
        float gv[4];
#pragma unroll
        for (int gi = 0; gi < 4; ++gi) {
            f32x4 a1 = {0.f, 0.f, 0.f, 0.f};
#pragma unroll
            for (int kt = 0; kt < 4; ++kt)
                a1 = __builtin_amdgcn_mfma_f32_16x16x32_f16(A[kt], Bf[gi][kt], a1, 0, 0, 0);
            gv[gi] = a1[0] + a1[1];   // row0 (h_hi*W) + row1 (h_lo*W)
        }

        // wave-local nonlinearity on lanes 0..15 (cells 16w..16w+15)
        if (lane < 16) {
            float i_ = fsig(gv[0] + xq0.x);
            float f_ = fsig(gv[1] + xq0.y);
            float g_ = ftanh(gv[2] + xq0.z);
            float o_ = fsig(gv[3] + xq0.w);
            c_reg = f_ * c_reg + i_ * g_;
            float h = o_ * ftanh(c_reg);
            h_last = h;
            ysb[(size_t)s * 128 + cell] = h;     // fire-and-forget store

            int kt = cell >> 5, kl = cell & 31;
            int slot = ((kl >> 2) & 3) * 2;
            int elem = (kl >> 4) * 4 + (kl & 3);
            _Float16 hh = (_Float16)h;
            afrag[wb][kt][slot + 0][elem] = hh;
            afrag[wb][kt][slot + 1][elem] = (_Float16)(h - (float)hh);
        }

        // LDS-only barrier: do NOT drain vmcnt (loads/stores stay in flight)
        __builtin_amdgcn_sched_barrier(0);
        asm volatile("s_waitcnt lgkmcnt(0)" ::: "memory");
        __builtin_amdgcn_s_barrier();
        __builtin_amdgcn_sched_barrier(0);

        xq0 = xq1; xq1 = xn;
    }

    if (lane < 16) {
        hn[b * 128 + cell] = h_last;
        cn[b * 128 + cell] = c_reg;
    }
}

// ---------------------------------------------------------------------------
// Kernel 3: fused flash attention (Q=K=V=ys, unscaled) + residual + fc.
// (unchanged -- becomes the top dispatch; next round's target)
// ---------------------------------------------------------------------------
__global__ __launch_bounds__(256) void attn_kernel(
    const float* __restrict__ ys, const float* __restrict__ fc_w,
    const float* __restrict__ fc_b, float* __restrict__ out)
{
    extern __shared__ float sm[];
    float* Qs = sm;                // 64*128
    float* KVs = sm + 64 * 128;    // 64*128
    float* Ps = sm + 2 * 64 * 128; // 64*68 (padded stride)

    const int b = blockIdx.y, qt = blockIdx.x;
    const int t = threadIdx.x;
    const int tr = t >> 4, tc = t & 15;
    const float* Yb = ys + (size_t)b * 2048 * 128;

#pragma unroll
    for (int i = 0; i < 8; ++i) {
        int idx = t + i * 256;
        int r = idx >> 5, c = (idx & 31) * 4;
        *(float4*)&Qs[r * 128 + c] = *(const float4*)&Yb[((size_t)qt * 64 + r) * 128 + c];
    }

    float m_i[4], l_i[4], o_acc[4][8];
#pragma unroll
    for (int i = 0; i < 4; ++i) {
        m_i[i] = -1e30f; l_i[i] = 0.f;
#pragma unroll
        for (int j = 0; j < 8; ++j) o_acc[i][j] = 0.f;
    }

    for (int kt = 0; kt < 32; ++kt) {
        __syncthreads();
#pragma unroll
        for (int i = 0; i < 8; ++i) {
            int idx = t + i * 256;
            int r = idx >> 5, c = (idx & 31) * 4;
            *(float4*)&KVs[r * 128 + c] = *(const float4*)&Yb[((size_t)kt * 64 + r) * 128 + c];
        }
        __syncthreads();

        float s[4][4];
#pragma unroll
        for (int i = 0; i < 4; ++i)
#pragma unroll
            for (int j = 0; j < 4; ++j) s[i][j] = 0.f;

#pragma unroll 8
        for (int c = 0; c < 32; ++c) {
            int cc4 = ((c + tc) & 31) << 2;
            float4 q[4], k[4];
#pragma unroll
            for (int i = 0; i < 4; ++i) q[i] = *(const float4*)&Qs[(tr * 4 + i) * 128 + cc4];
#pragma unroll
            for (int j = 0; j < 4; ++j) k[j] = *(const float4*)&KVs[(tc * 4 + j) * 128 + cc4];
#pragma unroll
            for (int i = 0; i < 4; ++i)
#pragma unroll
                for (int j = 0; j < 4; ++j)
                    s[i][j] += q[i].x * k[j].x + q[i].y * k[j].y + q[i].z * k[j].z + q[i].w * k[j].w;
        }

#pragma unroll
        for (int i = 0; i < 4; ++i) {
            float mx = fmaxf(fmaxf(s[i][0], s[i][1]), fmaxf(s[i][2], s[i][3]));
#pragma unroll
            for (int off = 1; off < 16; off <<= 1)
                mx = fmaxf(mx, __shfl_xor(mx, off));
            float mnew = fmaxf(m_i[i], mx);
            float scale = __expf(m_i[i] - mnew);
            m_i[i] = mnew;
            float4 p;
            p.x = __expf(s[i][0] - mnew);
            p.y = __expf(s[i][1] - mnew);
            p.z = __expf(s[i][2] - mnew);
            p.w = __expf(s[i][3] - mnew);
            float rs = p.x + p.y + p.z + p.w;
#pragma unroll
            for (int off = 1; off < 16; off <<= 1)
                rs += __shfl_xor(rs, off);
            l_i[i] = l_i[i] * scale + rs;
            *(float4*)&Ps[(tr * 4 + i) * 68 + tc * 4] = p;
#pragma unroll
            for (int d = 0; d < 8; ++d) o_acc[i][d] *= scale;
        }
        __syncthreads();

#pragma unroll 4
        for (int k4 = 0; k4 < 16; ++k4) {
            float pl[4][4];
#pragma unroll
            for (int i = 0; i < 4; ++i) {
                float4 p = *(const float4*)&Ps[(tr * 4 + i) * 68 + k4 * 4];
                pl[i][0] = p.x; pl[i][1] = p.y; pl[i][2] = p.z; pl[i][3] = p.w;
            }
#pragma unroll
            for (int kk = 0; kk < 4; ++kk) {
                int k = k4 * 4 + kk;
                float4 v0 = *(const float4*)&KVs[k * 128 + tc * 4];
                float4 v1 = *(const float4*)&KVs[k * 128 + 64 + tc * 4];
#pragma unroll
                for (int i = 0; i < 4; ++i) {
                    float pv = pl[i][kk];
                    o_acc[i][0] += pv * v0.x; o_acc[i][1] += pv * v0.y;
                    o_acc[i][2] += pv * v0.z; o_acc[i][3] += pv * v0.w;
                    o_acc[i][4] += pv * v1.x; o_acc[i][5] += pv * v1.y;
                    o_acc[i][6] += pv * v1.z; o_acc[i][7] += pv * v1.w;
                }
            }
        }
    }

    __syncthreads();
#pragma unroll
    for (int i = 0; i < 4; ++i) {
        float inv_l = 1.0f / l_i[i];
        int row = tr * 4 + i;
        float4 a0, a1;
        a0.x = Qs[row * 128 + tc * 4 + 0] + o_acc[i][0] * inv_l;
        a0.y = Qs[row * 128 + tc * 4 + 1] + o_acc[i][1] * inv_l;
        a0.z = Qs[row * 128 + tc * 4 + 2] + o_acc[i][2] * inv_l;
        a0.w = Qs[row * 128 + tc * 4 + 3] + o_acc[i][3] * inv_l;
        a1.x = Qs[row * 128 + 64 + tc * 4 + 0] + o_acc[i][4] * inv_l;
        a1.y = Qs[row * 128 + 64 + tc * 4 + 1] + o_acc[i][5] * inv_l;
        a1.z = Qs[row * 128 + 64 + tc * 4 + 2] + o_acc[i][6] * inv_l;
        a1.w = Qs[row * 128 + 64 + tc * 4 + 3] + o_acc[i][7] * inv_l;
        *(float4*)&KVs[row * 128 + tc * 4] = a0;
        *(float4*)&KVs[row * 128 + 64 + tc * 4] = a1;
    }
    __syncthreads();
#pragma unroll
    for (int i = 0; i < 8; ++i) {
        int idx = t + i * 256;
        int r = idx >> 5, c = (idx & 31) * 4;
        *(float4*)&Qs[r * 128 + c] = *(const float4*)&fc_w[r * 128 + c];
    }
    __syncthreads();

    float accf[4][4];
#pragma unroll
    for (int i = 0; i < 4; ++i)
#pragma unroll
        for (int j = 0; j < 4; ++j) accf[i][j] = 0.f;
#pragma unroll 8
    for (int c = 0; c < 32; ++c) {
        int cc4 = ((c + tc) & 31) << 2;
        float4 a[4], wv[4];
#pragma unroll
        for (int i = 0; i < 4; ++i) a[i] = *(const float4*)&KVs[(tr * 4 + i) * 128 + cc4];
#pragma unroll
        for (int j = 0; j < 4; ++j) wv[j] = *(const float4*)&Qs[(tc * 4 + j) * 128 + cc4];
#pragma unroll
        for (int i = 0; i < 4; ++i)
#pragma unroll
            for (int j = 0; j < 4; ++j)
                accf[i][j] += a[i].x * wv[j].x + a[i].y * wv[j].y + a[i].z * wv[j].z + a[i].w * wv[j].w;
    }

    float bj0 = fc_b[tc * 4 + 0], bj1 = fc_b[tc * 4 + 1];
    float bj2 = fc_b[tc * 4 + 2], bj3 = fc_b[tc * 4 + 3];
#pragma unroll
    for (int i = 0; i < 4; ++i) {
        float4 r;
        r.x = accf[i][0] + bj0; r.y = accf[i][1] + bj1;
        r.z = accf[i][2] + bj2; r.w = accf[i][3] + bj3;
        *(float4*)&out[((size_t)b * 2048 + (size_t)qt * 64 + tr * 4 + i) * 64 + tc * 4] = r;
    }
}

// ---------------------------------------------------------------------------
extern "C" void kernel_launch(void* const* d_in, const int* in_sizes, int n_in,
                              void* d_out, int out_size, void* d_ws, size_t ws_size,
                              hipStream_t stream) {
    const float* x   = (const float*)d_in[0];
    const float* h0  = (const float*)d_in[1];
    const float* c0  = (const float*)d_in[2];
    const float* Wih = (const float*)d_in[3];
    const float* Whh = (const float*)d_in[4];
    const float* bih = (const float*)d_in[5];
    const float* bhh = (const float*)d_in[6];
    const float* fcw = (const float*)d_in[7];
    const float* fcb = (const float*)d_in[8];
    (void)in_sizes; (void)n_in; (void)out_size; (void)ws_size;

    float* out = (float*)d_out;
    float* hn = out + (size_t)8 * 2048 * 64;
    float* cn = hn + 1024;

    float* xp2 = (float*)d_ws;                       // 8*2048*512 fp32 = 32 MB
    float* ys  = xp2 + (size_t)8 * 2048 * 512;       // 8*2048*128 fp32 = 8 MB

    xproj_kernel<<<2048, 256, 0, stream>>>(x, Wih, bih, bhh, xp2);
    lstm_kernel<<<8, 512, 0, stream>>>(xp2, Whh, h0, c0, ys, hn, cn);
    dim3 grid_attn(32, 8);
    attn_kernel<<<grid_attn, 256, 82944, stream>>>(ys, fcw, fcb, out);
}

// Round 4
// 1346.653 us; speedup vs baseline: 2.4488x; 1.4065x over previous
//
#include <hip/hip_runtime.h>
#include <cstddef>
#include <cstdint>

// Problem: B=8, S=2048, IN=64, H=128, OUT=64. All fp32.
// out = [8,2048,64] (1,048,576) ++ hn [1,8,128] (1024) ++ cn [1,8,128] (1024)

using short8 = __attribute__((ext_vector_type(8))) short;
using half8  = __attribute__((ext_vector_type(8))) _Float16;
using f32x4  = __attribute__((ext_vector_type(4))) float;

#define LOG2E  1.4426950408889634f
#define LOG2E2 2.8853900817779268f

// ---------------------------------------------------------------------------
// Kernel 1: x_proj, stored INTERLEAVED and PRE-SCALED by log2(e):
//   xp2[((b*2048+s)*128 + cell)*4 + part] = log2e * (x@W_ih + b_ih + b_hh)
// part 0..3 = i,f,g,o gate pre-activations for that cell.
// ---------------------------------------------------------------------------
__global__ __launch_bounds__(256) void xproj_kernel(
    const float* __restrict__ x, const float* __restrict__ W_ih,
    const float* __restrict__ b_ih, const float* __restrict__ b_hh,
    float* __restrict__ xp2)
{
    __shared__ __align__(16) float xs[8][64];
    const int t = threadIdx.x;
    const long row0 = (long)blockIdx.x * 8;

    if (t < 128) {
        int r = t >> 4, c4 = (t & 15) * 4;
        *(float4*)&xs[r][c4] = *(const float4*)&x[(row0 + r) * 64 + c4];
    }
    __syncthreads();

    const int g0 = t, g1 = t + 256;
    float acc0[8], acc1[8];
#pragma unroll
    for (int r = 0; r < 8; ++r) { acc0[r] = 0.f; acc1[r] = 0.f; }

#pragma unroll
    for (int c = 0; c < 16; ++c) {
        float4 w0 = *(const float4*)&W_ih[g0 * 64 + c * 4];
        float4 w1 = *(const float4*)&W_ih[g1 * 64 + c * 4];
#pragma unroll
        for (int r = 0; r < 8; ++r) {
            float4 xv = *(const float4*)&xs[r][c * 4];
            acc0[r] += w0.x * xv.x + w0.y * xv.y + w0.z * xv.z + w0.w * xv.w;
            acc1[r] += w1.x * xv.x + w1.y * xv.y + w1.z * xv.z + w1.w * xv.w;
        }
    }
    const float bb0 = b_ih[g0] + b_hh[g0];
    const float bb1 = b_ih[g1] + b_hh[g1];
    const int c0i = g0 & 127, p0 = g0 >> 7;
    const int c1i = g1 & 127, p1 = g1 >> 7;
#pragma unroll
    for (int r = 0; r < 8; ++r) {
        xp2[((row0 + r) * 128 + c0i) * 4 + p0] = (acc0[r] + bb0) * LOG2E;
        xp2[((row0 + r) * 128 + c1i) * 4 + p1] = (acc1[r] + bb1) * LOG2E;
    }
}

// ---------------------------------------------------------------------------
// Kernel 2: MFMA LSTM v3 (VALU-slimmed). 8 blocks x 512 thr (8 waves).
//  - fp16 W_hh pre-scaled by log2e resident in VGPRs (64/thread)
//  - h Dekker-split hi/lo rides A rows 0/1 of one mfma_16x16x32_f16
//  - persistent A regs: rows 2..15 zeroed ONCE; exec-masked ds_read
//    refreshes lanes l16<2 only (inactive lanes keep zeros forever)
//  - even/odd unrolled bodies -> LDS offsets are immediates
//  - nonlin in exp2 domain with v_exp/v_rcp (no IEEE div)
//  - raw s_barrier + lgkmcnt(0) only; global loads/stores never drained
// ---------------------------------------------------------------------------
__global__ __launch_bounds__(512, 2) void lstm_kernel(
    const float* __restrict__ xp2, const float* __restrict__ W_hh,
    const float* __restrict__ h0, const float* __restrict__ c0,
    float* __restrict__ ys, float* __restrict__ hn, float* __restrict__ cn)
{
    const int b    = blockIdx.x;     // 0..7
    const int t    = threadIdx.x;    // 0..511
    const int w    = t >> 6;         // wave 0..7
    const int lane = t & 63;
    const int l16  = lane & 15;
    const int sub  = lane >> 4;      // 0..3

    // [buf][ktile][slot][elem] fp16, 2 KB. slot = sub*2 + row(0=hi,1=lo)
    __shared__ __align__(16) _Float16 afrag[2][4][8][8];

    // ---- pack W_hh * log2e fragments once.
    // k-bijection shared with A: k = kt*32 + (j>>2)*16 + sub*4 + (j&3)
    half8 Bf[4][4];   // [gate-tile][ktile] = 64 VGPRs
#pragma unroll
    for (int gi = 0; gi < 4; ++gi) {
        const int gate = (w + 8 * gi) * 16 + l16;
#pragma unroll
        for (int kt = 0; kt < 4; ++kt) {
            half8 v;
#pragma unroll
            for (int j = 0; j < 8; ++j) {
                int k = kt * 32 + (j >> 2) * 16 + sub * 4 + (j & 3);
                v[j] = (_Float16)(W_hh[gate * 128 + k] * LOG2E);
            }
            Bf[gi][kt] = v;
        }
    }

    const int cell = w * 16 + l16;   // meaningful for lanes 0..15
    float c_reg = 0.f, h_last = 0.f;

    // write addresses (lanes<16): cell -> (kt, slot-pair, elem)
    const int wkt   = cell >> 5;
    const int wkl   = cell & 31;
    const int wslot = ((wkl >> 2) & 3) * 2;
    const int welem = (wkl >> 4) * 4 + (wkl & 3);
    _Float16* whi = &afrag[0][wkt][wslot + 0][welem];
    _Float16* wlo = &afrag[0][wkt][wslot + 1][welem];

    // read base (meaningful for lanes l16<2): slot = sub*2 + l16
    const _Float16* aread = &afrag[0][0][sub * 2 + (l16 & 1)][0];

    if (lane < 16) {
        c_reg  = c0[b * 128 + cell];
        h_last = h0[b * 128 + cell];
        _Float16 hh = (_Float16)h_last;
        whi[0] = hh;                              // buf 0
        wlo[0] = (_Float16)(h_last - (float)hh);
    }
    __syncthreads();

    const float* xpl = xp2 + (size_t)b * 2048 * 512 + cell * 4;
    float*       yp  = ys  + (size_t)b * 2048 * 128 + cell;

    // persistent A fragments; rows 2..15 (lanes l16>=2) stay zero forever
    half8 A[4];
#pragma unroll
    for (int kt = 0; kt < 4; ++kt)
#pragma unroll
        for (int j = 0; j < 8; ++j) A[kt][j] = (_Float16)0.f;

    float4 xqA = *(const float4*)xpl;           // step 0 (scaled preacts)
    float4 xqB = *(const float4*)(xpl + 512);   // step 1
    const float* pA = xpl + 1024;               // prefetch ptr, even steps
    const float* pB = xpl + 1536;               // prefetch ptr, odd steps
    // (last-iteration prefetches land past xp2 into the ys region of d_ws --
    //  valid memory, values unused)

#define LSTM_STEP(RB, WB, XQV, PP)                                            \
    {                                                                         \
        if (l16 < 2) {                                                        \
            A[0] = *(const half8*)(aread + (RB) * 256 + 0);                   \
            A[1] = *(const half8*)(aread + (RB) * 256 + 64);                  \
            A[2] = *(const half8*)(aread + (RB) * 256 + 128);                 \
            A[3] = *(const half8*)(aread + (RB) * 256 + 192);                 \
        }                                                                     \
        float4 xnew = *(const float4*)(PP); (PP) += 1024;                     \
        f32x4 ac0 = {0.f, 0.f, 0.f, 0.f};                                     \
        f32x4 ac1 = ac0, ac2 = ac0, ac3 = ac0;                                \
        _Pragma("unroll")                                                     \
        for (int kt = 0; kt < 4; ++kt) {                                      \
            ac0 = __builtin_amdgcn_mfma_f32_16x16x32_f16(A[kt], Bf[0][kt], ac0, 0, 0, 0); \
            ac1 = __builtin_amdgcn_mfma_f32_16x16x32_f16(A[kt], Bf[1][kt], ac1, 0, 0, 0); \
            ac2 = __builtin_amdgcn_mfma_f32_16x16x32_f16(A[kt], Bf[2][kt], ac2, 0, 0, 0); \
            ac3 = __builtin_amdgcn_mfma_f32_16x16x32_f16(A[kt], Bf[3][kt], ac3, 0, 0, 0); \
        }                                                                     \
        if (lane < 16) {                                                      \
            float gi_ = ac0[0] + ac0[1] + (XQV).x;                            \
            float gf_ = ac1[0] + ac1[1] + (XQV).y;                            \
            float gg_ = ac2[0] + ac2[1] + (XQV).z;                            \
            float go_ = ac3[0] + ac3[1] + (XQV).w;                            \
            float i_ = __builtin_amdgcn_rcpf(1.f + __builtin_amdgcn_exp2f(-gi_)); \
            float f_ = __builtin_amdgcn_rcpf(1.f + __builtin_amdgcn_exp2f(-gf_)); \
            float o_ = __builtin_amdgcn_rcpf(1.f + __builtin_amdgcn_exp2f(-go_)); \
            float g_ = 1.f - 2.f * __builtin_amdgcn_rcpf(1.f + __builtin_amdgcn_exp2f(gg_ + gg_)); \
            c_reg = f_ * c_reg + i_ * g_;                                     \
            float tc_ = 1.f - 2.f * __builtin_amdgcn_rcpf(1.f + __builtin_amdgcn_exp2f(c_reg * LOG2E2)); \
            float h = o_ * tc_;                                               \
            h_last = h;                                                       \
            *yp = h;                                                          \
            _Float16 hh = (_Float16)h;                                        \
            whi[(WB) * 256] = hh;                                             \
            wlo[(WB) * 256] = (_Float16)(h - (float)hh);                      \
        }                                                                     \
        yp += 128;                                                            \
        (XQV) = xnew;                                                         \
        __builtin_amdgcn_sched_barrier(0);                                    \
        asm volatile("s_waitcnt lgkmcnt(0)" ::: "memory");                    \
        __builtin_amdgcn_s_barrier();                                         \
        __builtin_amdgcn_sched_barrier(0);                                    \
    }

    for (int s = 0; s < 2048; s += 2) {
        LSTM_STEP(0, 1, xqA, pA)   // even: read buf0, write buf1
        LSTM_STEP(1, 0, xqB, pB)   // odd:  read buf1, write buf0
    }
#undef LSTM_STEP

    if (lane < 16) {
        hn[b * 128 + cell] = h_last;
        cn[b * 128 + cell] = c_reg;
    }
}

// ---------------------------------------------------------------------------
// Kernel 3: fused flash attention (Q=K=V=ys, unscaled) + residual + fc.
// (unchanged -- next round's target)
// ---------------------------------------------------------------------------
__global__ __launch_bounds__(256) void attn_kernel(
    const float* __restrict__ ys, const float* __restrict__ fc_w,
    const float* __restrict__ fc_b, float* __restrict__ out)
{
    extern __shared__ float sm[];
    float* Qs = sm;                // 64*128
    float* KVs = sm + 64 * 128;    // 64*128
    float* Ps = sm + 2 * 64 * 128; // 64*68 (padded stride)

    const int b = blockIdx.y, qt = blockIdx.x;
    const int t = threadIdx.x;
    const int tr = t >> 4, tc = t & 15;
    const float* Yb = ys + (size_t)b * 2048 * 128;

#pragma unroll
    for (int i = 0; i < 8; ++i) {
        int idx = t + i * 256;
        int r = idx >> 5, c = (idx & 31) * 4;
        *(float4*)&Qs[r * 128 + c] = *(const float4*)&Yb[((size_t)qt * 64 + r) * 128 + c];
    }

    float m_i[4], l_i[4], o_acc[4][8];
#pragma unroll
    for (int i = 0; i < 4; ++i) {
        m_i[i] = -1e30f; l_i[i] = 0.f;
#pragma unroll
        for (int j = 0; j < 8; ++j) o_acc[i][j] = 0.f;
    }

    for (int kt = 0; kt < 32; ++kt) {
        __syncthreads();
#pragma unroll
        for (int i = 0; i < 8; ++i) {
            int idx = t + i * 256;
            int r = idx >> 5, c = (idx & 31) * 4;
            *(float4*)&KVs[r * 128 + c] = *(const float4*)&Yb[((size_t)kt * 64 + r) * 128 + c];
        }
        __syncthreads();

        float s[4][4];
#pragma unroll
        for (int i = 0; i < 4; ++i)
#pragma unroll
            for (int j = 0; j < 4; ++j) s[i][j] = 0.f;

#pragma unroll 8
        for (int c = 0; c < 32; ++c) {
            int cc4 = ((c + tc) & 31) << 2;
            float4 q[4], k[4];
#pragma unroll
            for (int i = 0; i < 4; ++i) q[i] = *(const float4*)&Qs[(tr * 4 + i) * 128 + cc4];
#pragma unroll
            for (int j = 0; j < 4; ++j) k[j] = *(const float4*)&KVs[(tc * 4 + j) * 128 + cc4];
#pragma unroll
            for (int i = 0; i < 4; ++i)
#pragma unroll
                for (int j = 0; j < 4; ++j)
                    s[i][j] += q[i].x * k[j].x + q[i].y * k[j].y + q[i].z * k[j].z + q[i].w * k[j].w;
        }

#pragma unroll
        for (int i = 0; i < 4; ++i) {
            float mx = fmaxf(fmaxf(s[i][0], s[i][1]), fmaxf(s[i][2], s[i][3]));
#pragma unroll
            for (int off = 1; off < 16; off <<= 1)
                mx = fmaxf(mx, __shfl_xor(mx, off));
            float mnew = fmaxf(m_i[i], mx);
            float scale = __expf(m_i[i] - mnew);
            m_i[i] = mnew;
            float4 p;
            p.x = __expf(s[i][0] - mnew);
            p.y = __expf(s[i][1] - mnew);
            p.z = __expf(s[i][2] - mnew);
            p.w = __expf(s[i][3] - mnew);
            float rs = p.x + p.y + p.z + p.w;
#pragma unroll
            for (int off = 1; off < 16; off <<= 1)
                rs += __shfl_xor(rs, off);
            l_i[i] = l_i[i] * scale + rs;
            *(float4*)&Ps[(tr * 4 + i) * 68 + tc * 4] = p;
#pragma unroll
            for (int d = 0; d < 8; ++d) o_acc[i][d] *= scale;
        }
        __syncthreads();

#pragma unroll 4
        for (int k4 = 0; k4 < 16; ++k4) {
            float pl[4][4];
#pragma unroll
            for (int i = 0; i < 4; ++i) {
                float4 p = *(const float4*)&Ps[(tr * 4 + i) * 68 + k4 * 4];
                pl[i][0] = p.x; pl[i][1] = p.y; pl[i][2] = p.z; pl[i][3] = p.w;
            }
#pragma unroll
            for (int kk = 0; kk < 4; ++kk) {
                int k = k4 * 4 + kk;
                float4 v0 = *(const float4*)&KVs[k * 128 + tc * 4];
                float4 v1 = *(const float4*)&KVs[k * 128 + 64 + tc * 4];
#pragma unroll
                for (int i = 0; i < 4; ++i) {
                    float pv = pl[i][kk];
                    o_acc[i][0] += pv * v0.x; o_acc[i][1] += pv * v0.y;
                    o_acc[i][2] += pv * v0.z; o_acc[i][3] += pv * v0.w;
                    o_acc[i][4] += pv * v1.x; o_acc[i][5] += pv * v1.y;
                    o_acc[i][6] += pv * v1.z; o_acc[i][7] += pv * v1.w;
                }
            }
        }
    }

    __syncthreads();
#pragma unroll
    for (int i = 0; i < 4; ++i) {
        float inv_l = 1.0f / l_i[i];
        int row = tr * 4 + i;
        float4 a0, a1;
        a0.x = Qs[row * 128 + tc * 4 + 0] + o_acc[i][0] * inv_l;
        a0.y = Qs[row * 128 + tc * 4 + 1] + o_acc[i][1] * inv_l;
        a0.z = Qs[row * 128 + tc * 4 + 2] + o_acc[i][2] * inv_l;
        a0.w = Qs[row * 128 + tc * 4 + 3] + o_acc[i][3] * inv_l;
        a1.x = Qs[row * 128 + 64 + tc * 4 + 0] + o_acc[i][4] * inv_l;
        a1.y = Qs[row * 128 + 64 + tc * 4 + 1] + o_acc[i][5] * inv_l;
        a1.z = Qs[row * 128 + 64 + tc * 4 + 2] + o_acc[i][6] * inv_l;
        a1.w = Qs[row * 128 + 64 + tc * 4 + 3] + o_acc[i][7] * inv_l;
        *(float4*)&KVs[row * 128 + tc * 4] = a0;
        *(float4*)&KVs[row * 128 + 64 + tc * 4] = a1;
    }
    __syncthreads();
#pragma unroll
    for (int i = 0; i < 8; ++i) {
        int idx = t + i * 256;
        int r = idx >> 5, c = (idx & 31) * 4;
        *(float4*)&Qs[r * 128 + c] = *(const float4*)&fc_w[r * 128 + c];
    }
    __syncthreads();

    float accf[4][4];
#pragma unroll
    for (int i = 0; i < 4; ++i)
#pragma unroll
        for (int j = 0; j < 4; ++j) accf[i][j] = 0.f;
#pragma unroll 8
    for (int c = 0; c < 32; ++c) {
        int cc4 = ((c + tc) & 31) << 2;
        float4 a[4], wv[4];
#pragma unroll
        for (int i = 0; i < 4; ++i) a[i] = *(const float4*)&KVs[(tr * 4 + i) * 128 + cc4];
#pragma unroll
        for (int j = 0; j < 4; ++j) wv[j] = *(const float4*)&Qs[(tc * 4 + j) * 128 + cc4];
#pragma unroll
        for (int i = 0; i < 4; ++i)
#pragma unroll
            for (int j = 0; j < 4; ++j)
                accf[i][j] += a[i].x * wv[j].x + a[i].y * wv[j].y + a[i].z * wv[j].z + a[i].w * wv[j].w;
    }

    float bj0 = fc_b[tc * 4 + 0], bj1 = fc_b[tc * 4 + 1];
    float bj2 = fc_b[tc * 4 + 2], bj3 = fc_b[tc * 4 + 3];
#pragma unroll
    for (int i = 0; i < 4; ++i) {
        float4 r;
        r.x = accf[i][0] + bj0; r.y = accf[i][1] + bj1;
        r.z = accf[i][2] + bj2; r.w = accf[i][3] + bj3;
        *(float4*)&out[((size_t)b * 2048 + (size_t)qt * 64 + tr * 4 + i) * 64 + tc * 4] = r;
    }
}

// ---------------------------------------------------------------------------
extern "C" void kernel_launch(void* const* d_in, const int* in_sizes, int n_in,
                              void* d_out, int out_size, void* d_ws, size_t ws_size,
                              hipStream_t stream) {
    const float* x   = (const float*)d_in[0];
    const float* h0  = (const float*)d_in[1];
    const float* c0  = (const float*)d_in[2];
    const float* Wih = (const float*)d_in[3];
    const float* Whh = (const float*)d_in[4];
    const float* bih = (const float*)d_in[5];
    const float* bhh = (const float*)d_in[6];
    const float* fcw = (const float*)d_in[7];
    const float* fcb = (const float*)d_in[8];
    (void)in_sizes; (void)n_in; (void)out_size; (void)ws_size;

    float* out = (float*)d_out;
    float* hn = out + (size_t)8 * 2048 * 64;
    float* cn = hn + 1024;

    float* xp2 = (float*)d_ws;                       // 8*2048*512 fp32 = 32 MB
    float* ys  = xp2 + (size_t)8 * 2048 * 512;       // 8*2048*128 fp32 = 8 MB

    xproj_kernel<<<2048, 256, 0, stream>>>(x, Wih, bih, bhh, xp2);
    lstm_kernel<<<8, 512, 0, stream>>>(xp2, Whh, h0, c0, ys, hn, cn);
    dim3 grid_attn(32, 8);
    attn_kernel<<<grid_attn, 256, 82944, stream>>>(ys, fcw, fcb, out);
}

// Round 7
// 1048.825 us; speedup vs baseline: 3.1441x; 1.2840x over previous
//
#include <hip/hip_runtime.h>
#include <cstddef>
#include <cstdint>

// Problem: B=8, S=2048, IN=64, H=128, OUT=64. All fp32.
// out = [8,2048,64] (1,048,576) ++ hn [1,8,128] (1024) ++ cn [1,8,128] (1024)

using short8 = __attribute__((ext_vector_type(8))) short;
using half8  = __attribute__((ext_vector_type(8))) _Float16;
using f32x4  = __attribute__((ext_vector_type(4))) float;

#define LOG2E  1.4426950408889634f
#define LOG2E2 2.8853900817779268f

__device__ __forceinline__ unsigned short f2h(float f) {
    return __builtin_bit_cast(unsigned short, (_Float16)f);
}

union H8U { half8 h; uint4 u; ushort us[8]; };
__device__ __forceinline__ half8 h8_from(uint2 a, uint2 b) {
    H8U x; x.u = make_uint4(a.x, a.y, b.x, b.y); return x.h;
}

// ---------------------------------------------------------------------------
// Kernel 1: x_proj, interleaved + pre-scaled by log2(e):
//   xp2[((b*2048+s)*128 + cell)*4 + part] = log2e*(x@W_ih + b_ih + b_hh)
// ---------------------------------------------------------------------------
__global__ __launch_bounds__(256) void xproj_kernel(
    const float* __restrict__ x, const float* __restrict__ W_ih,
    const float* __restrict__ b_ih, const float* __restrict__ b_hh,
    float* __restrict__ xp2)
{
    __shared__ __align__(16) float xs[8][64];
    const int t = threadIdx.x;
    const long row0 = (long)blockIdx.x * 8;

    if (t < 128) {
        int r = t >> 4, c4 = (t & 15) * 4;
        *(float4*)&xs[r][c4] = *(const float4*)&x[(row0 + r) * 64 + c4];
    }
    __syncthreads();

    const int g0 = t, g1 = t + 256;
    float acc0[8], acc1[8];
#pragma unroll
    for (int r = 0; r < 8; ++r) { acc0[r] = 0.f; acc1[r] = 0.f; }

#pragma unroll
    for (int c = 0; c < 16; ++c) {
        float4 w0 = *(const float4*)&W_ih[g0 * 64 + c * 4];
        float4 w1 = *(const float4*)&W_ih[g1 * 64 + c * 4];
#pragma unroll
        for (int r = 0; r < 8; ++r) {
            float4 xv = *(const float4*)&xs[r][c * 4];
            acc0[r] += w0.x * xv.x + w0.y * xv.y + w0.z * xv.z + w0.w * xv.w;
            acc1[r] += w1.x * xv.x + w1.y * xv.y + w1.z * xv.z + w1.w * xv.w;
        }
    }
    const float bb0 = b_ih[g0] + b_hh[g0];
    const float bb1 = b_ih[g1] + b_hh[g1];
    const int c0i = g0 & 127, p0 = g0 >> 7;
    const int c1i = g1 & 127, p1 = g1 >> 7;
#pragma unroll
    for (int r = 0; r < 8; ++r) {
        xp2[((row0 + r) * 128 + c0i) * 4 + p0] = (acc0[r] + bb0) * LOG2E;
        xp2[((row0 + r) * 128 + c1i) * 4 + p1] = (acc1[r] + bb1) * LOG2E;
    }
}

// ---------------------------------------------------------------------------
// Kernel 2: MFMA LSTM (unchanged from round 4; 917 us, model-validated).
// ---------------------------------------------------------------------------
__global__ __launch_bounds__(512, 2) void lstm_kernel(
    const float* __restrict__ xp2, const float* __restrict__ W_hh,
    const float* __restrict__ h0, const float* __restrict__ c0,
    float* __restrict__ ys, float* __restrict__ hn, float* __restrict__ cn)
{
    const int b    = blockIdx.x;
    const int t    = threadIdx.x;
    const int w    = t >> 6;
    const int lane = t & 63;
    const int l16  = lane & 15;
    const int sub  = lane >> 4;

    __shared__ __align__(16) _Float16 afrag[2][4][8][8];

    half8 Bf[4][4];
#pragma unroll
    for (int gi = 0; gi < 4; ++gi) {
        const int gate = (w + 8 * gi) * 16 + l16;
#pragma unroll
        for (int kt = 0; kt < 4; ++kt) {
            half8 v;
#pragma unroll
            for (int j = 0; j < 8; ++j) {
                int k = kt * 32 + (j >> 2) * 16 + sub * 4 + (j & 3);
                v[j] = (_Float16)(W_hh[gate * 128 + k] * LOG2E);
            }
            Bf[gi][kt] = v;
        }
    }

    const int cell = w * 16 + l16;
    float c_reg = 0.f, h_last = 0.f;

    const int wkt   = cell >> 5;
    const int wkl   = cell & 31;
    const int wslot = ((wkl >> 2) & 3) * 2;
    const int welem = (wkl >> 4) * 4 + (wkl & 3);
    _Float16* whi = &afrag[0][wkt][wslot + 0][welem];
    _Float16* wlo = &afrag[0][wkt][wslot + 1][welem];

    const _Float16* aread = &afrag[0][0][sub * 2 + (l16 & 1)][0];

    if (lane < 16) {
        c_reg  = c0[b * 128 + cell];
        h_last = h0[b * 128 + cell];
        _Float16 hh = (_Float16)h_last;
        whi[0] = hh;
        wlo[0] = (_Float16)(h_last - (float)hh);
    }
    __syncthreads();

    const float* xpl = xp2 + (size_t)b * 2048 * 512 + cell * 4;
    float*       yp  = ys  + (size_t)b * 2048 * 128 + cell;

    half8 A[4];
#pragma unroll
    for (int kt = 0; kt < 4; ++kt)
#pragma unroll
        for (int j = 0; j < 8; ++j) A[kt][j] = (_Float16)0.f;

    float4 xqA = *(const float4*)xpl;
    float4 xqB = *(const float4*)(xpl + 512);
    const float* pA = xpl + 1024;
    const float* pB = xpl + 1536;

#define LSTM_STEP(RB, WB, XQV, PP)                                            \
    {                                                                         \
        if (l16 < 2) {                                                        \
            A[0] = *(const half8*)(aread + (RB) * 256 + 0);                   \
            A[1] = *(const half8*)(aread + (RB) * 256 + 64);                  \
            A[2] = *(const half8*)(aread + (RB) * 256 + 128);                 \
            A[3] = *(const half8*)(aread + (RB) * 256 + 192);                 \
        }                                                                     \
        float4 xnew = *(const float4*)(PP); (PP) += 1024;                     \
        f32x4 ac0 = {0.f, 0.f, 0.f, 0.f};                                     \
        f32x4 ac1 = ac0, ac2 = ac0, ac3 = ac0;                                \
        _Pragma("unroll")                                                     \
        for (int kt = 0; kt < 4; ++kt) {                                      \
            ac0 = __builtin_amdgcn_mfma_f32_16x16x32_f16(A[kt], Bf[0][kt], ac0, 0, 0, 0); \
            ac1 = __builtin_amdgcn_mfma_f32_16x16x32_f16(A[kt], Bf[1][kt], ac1, 0, 0, 0); \
            ac2 = __builtin_amdgcn_mfma_f32_16x16x32_f16(A[kt], Bf[2][kt], ac2, 0, 0, 0); \
            ac3 = __builtin_amdgcn_mfma_f32_16x16x32_f16(A[kt], Bf[3][kt], ac3, 0, 0, 0); \
        }                                                                     \
        if (lane < 16) {                                                      \
            float gi_ = ac0[0] + ac0[1] + (XQV).x;                            \
            float gf_ = ac1[0] + ac1[1] + (XQV).y;                            \
            float gg_ = ac2[0] + ac2[1] + (XQV).z;                            \
            float go_ = ac3[0] + ac3[1] + (XQV).w;                            \
            float i_ = __builtin_amdgcn_rcpf(1.f + __builtin_amdgcn_exp2f(-gi_)); \
            float f_ = __builtin_amdgcn_rcpf(1.f + __builtin_amdgcn_exp2f(-gf_)); \
            float o_ = __builtin_amdgcn_rcpf(1.f + __builtin_amdgcn_exp2f(-go_)); \
            float g_ = 1.f - 2.f * __builtin_amdgcn_rcpf(1.f + __builtin_amdgcn_exp2f(gg_ + gg_)); \
            c_reg = f_ * c_reg + i_ * g_;                                     \
            float tc_ = 1.f - 2.f * __builtin_amdgcn_rcpf(1.f + __builtin_amdgcn_exp2f(c_reg * LOG2E2)); \
            float h = o_ * tc_;                                               \
            h_last = h;                                                       \
            *yp = h;                                                          \
            _Float16 hh = (_Float16)h;                                        \
            whi[(WB) * 256] = hh;                                             \
            wlo[(WB) * 256] = (_Float16)(h - (float)hh);                      \
        }                                                                     \
        yp += 128;                                                            \
        (XQV) = xnew;                                                         \
        __builtin_amdgcn_sched_barrier(0);                                    \
        asm volatile("s_waitcnt lgkmcnt(0)" ::: "memory");                    \
        __builtin_amdgcn_s_barrier();                                         \
        __builtin_amdgcn_sched_barrier(0);                                    \
    }

    for (int s = 0; s < 2048; s += 2) {
        LSTM_STEP(0, 1, xqA, pA)
        LSTM_STEP(1, 0, xqB, pB)
    }
#undef LSTM_STEP

    if (lane < 16) {
        hn[b * 128 + cell] = h_last;
        cn[b * 128 + cell] = c_reg;
    }
}

// ---------------------------------------------------------------------------
// Kernel 3: MFMA flash attention, ALL-C version (no inline asm).
// grid (32 qtiles, 8 b) = 256 blocks, 256 thr (4 waves, 16 q-rows each).
//  - swapped QK: S^T = mfma(K, Q*log2e); D col=q=l16, rows=kv (sub*4+reg);
//    softmax butterflied over sub-lanes (xor 16/32).
//  - Ks [kv][128] fp16 XOR-swizzled (^((kv&7)<<4) on the 8B d-group).
//  - Vc plain planes [8][64][16] fp16; PV A-frags gathered via scalar u16
//    LDS reads (compiler-managed waitcnts) -- isolates the former tr-read asm.
//  - P exchanged through per-wave LDS with plain stores/loads (same-wave,
//    compiler-ordered; no barrier needed).
//  - epilogue: out^T = fc @ (Y^T + C^T/l) via MFMA, all in-register.
// ---------------------------------------------------------------------------
__global__ __launch_bounds__(256) void attn_kernel(
    const float* __restrict__ ys, const float* __restrict__ fc_w,
    const float* __restrict__ fc_b, float* __restrict__ out)
{
    __shared__ __align__(16) ushort Ks[2][64 * 128];   // 32 KB, swizzled
    __shared__ __align__(16) ushort Vc[2][8][64][16];  // 32 KB, plain planes
    __shared__ __align__(16) ushort Pl[4][16][68];     // 8.5 KB, per-wave P

    const int b = blockIdx.y, qt = blockIdx.x;
    const int t = threadIdx.x;
    const int w = t >> 6, lane = t & 63, l16 = lane & 15, sub = lane >> 4;
    const float* Yb = ys + (size_t)b * 2048 * 128;

    // ---- Q fragments (fp16, pre-scaled by log2e). B-side: n=q=l16, k=d.
    const int qrow = qt * 64 + w * 16 + l16;
    half8 Qf[4];
#pragma unroll
    for (int kt = 0; kt < 4; ++kt) {
        float4 a0 = *(const float4*)&Yb[qrow * 128 + kt * 32 + sub * 4];
        float4 a1 = *(const float4*)&Yb[qrow * 128 + kt * 32 + 16 + sub * 4];
        half8 v;
        v[0] = (_Float16)(a0.x * LOG2E); v[1] = (_Float16)(a0.y * LOG2E);
        v[2] = (_Float16)(a0.z * LOG2E); v[3] = (_Float16)(a0.w * LOG2E);
        v[4] = (_Float16)(a1.x * LOG2E); v[5] = (_Float16)(a1.y * LOG2E);
        v[6] = (_Float16)(a1.z * LOG2E); v[7] = (_Float16)(a1.w * LOG2E);
        Qf[kt] = v;
    }

    float4 st[8];   // stage registers (load early, LDS-write late)
#define STAGE_LOAD(KVT)                                                      \
    {                                                                        \
        const float* src = Yb + (size_t)(KVT) * 64 * 128;                    \
        _Pragma("unroll")                                                    \
        for (int p = 0; p < 8; ++p) {                                        \
            int idx = p * 256 + t;                                           \
            st[p] = *(const float4*)&src[idx * 4];                           \
        }                                                                    \
    }
#define STAGE_WRITE(BUF)                                                     \
    {                                                                        \
        char* kbase = (char*)&Ks[BUF][0];                                    \
        _Pragma("unroll")                                                    \
        for (int p = 0; p < 8; ++p) {                                        \
            int idx = p * 256 + t;                                           \
            int kv = idx >> 5, d4 = (idx & 31) * 4;                          \
            ushort4 hv;                                                      \
            hv.x = f2h(st[p].x); hv.y = f2h(st[p].y);                        \
            hv.z = f2h(st[p].z); hv.w = f2h(st[p].w);                        \
            uint koff = (uint)((kv * 256 + d4 * 2) ^ ((kv & 7) << 4));       \
            *(ushort4*)(kbase + koff) = hv;                                  \
            *(ushort4*)&Vc[BUF][d4 >> 4][kv][d4 & 15] = hv;                  \
        }                                                                    \
    }

    // prologue: stage tile 0
    STAGE_LOAD(0)
    STAGE_WRITE(0)
    __syncthreads();

    float m_r = -1e30f, l_r = 0.f;
    f32x4 o[8];
#pragma unroll
    for (int dt = 0; dt < 8; ++dt) o[dt] = (f32x4){0.f, 0.f, 0.f, 0.f};

    for (int kvt = 0; kvt < 32; ++kvt) {
        const int rb = kvt & 1;
        if (kvt < 31) STAGE_LOAD(kvt + 1)

        // ---- QK: S^T[kv = rt*16+sub*4+reg][q = l16]
        const char* kp = (const char*)&Ks[rb][0];
        f32x4 s[4];
#pragma unroll
        for (int rt = 0; rt < 4; ++rt) {
            f32x4 sa = {0.f, 0.f, 0.f, 0.f};
            int row = rt * 16 + l16;
            int sw  = (row & 7) << 4;
#pragma unroll
            for (int kt = 0; kt < 4; ++kt) {
                int base0 = row * 256 + (kt * 32 + sub * 4) * 2;
                uint2 q0 = *(const uint2*)(kp + (base0 ^ sw));
                uint2 q1 = *(const uint2*)(kp + ((base0 + 32) ^ sw));
                sa = __builtin_amdgcn_mfma_f32_16x16x32_f16(h8_from(q0, q1), Qf[kt], sa, 0, 0, 0);
            }
            s[rt] = sa;
        }

        // ---- online softmax; butterfly over the 4 sub-lanes (xor 16/32)
        float pm = s[0][0];
#pragma unroll
        for (int rt = 0; rt < 4; ++rt)
#pragma unroll
            for (int r = 0; r < 4; ++r) pm = fmaxf(pm, s[rt][r]);
        pm = fmaxf(pm, __shfl_xor(pm, 16));
        pm = fmaxf(pm, __shfl_xor(pm, 32));
        float mnew = fmaxf(m_r, pm);
        float sc = __builtin_amdgcn_exp2f(m_r - mnew);
        m_r = mnew;
        float psum = 0.f;
        float pv[4][4];
#pragma unroll
        for (int rt = 0; rt < 4; ++rt)
#pragma unroll
            for (int r = 0; r < 4; ++r) {
                pv[rt][r] = __builtin_amdgcn_exp2f(s[rt][r] - mnew);
                psum += pv[rt][r];
            }
        psum += __shfl_xor(psum, 16);
        psum += __shfl_xor(psum, 32);
        l_r = l_r * sc + psum;
#pragma unroll
        for (int dt = 0; dt < 8; ++dt) {
            o[dt][0] *= sc; o[dt][1] *= sc; o[dt][2] *= sc; o[dt][3] *= sc;
        }

        // ---- P[q=l16][kv] exchange via per-wave LDS (plain C, same wave)
#pragma unroll
        for (int rt = 0; rt < 4; ++rt) {
            uint lo = (uint)f2h(pv[rt][0]) | ((uint)f2h(pv[rt][1]) << 16);
            uint hi = (uint)f2h(pv[rt][2]) | ((uint)f2h(pv[rt][3]) << 16);
            *(uint2*)&Pl[w][l16][rt * 16 + sub * 4] = make_uint2(lo, hi);
        }
        uint2 pf0 = *(const uint2*)&Pl[w][l16][0  + sub * 4];
        uint2 pf1 = *(const uint2*)&Pl[w][l16][16 + sub * 4];
        uint2 pf2 = *(const uint2*)&Pl[w][l16][32 + sub * 4];
        uint2 pf3 = *(const uint2*)&Pl[w][l16][48 + sub * 4];
        half8 pB0 = h8_from(pf0, pf1);
        half8 pB1 = h8_from(pf2, pf3);

        // ---- PV: context^T += V^T @ P; A gathered as scalar u16 reads
#pragma unroll
        for (int dt = 0; dt < 8; ++dt) {
            H8U A0u, A1u;
#pragma unroll
            for (int jj = 0; jj < 4; ++jj) {
                A0u.us[jj]     = Vc[rb][dt][     sub * 4 + jj][l16];
                A0u.us[jj + 4] = Vc[rb][dt][16 + sub * 4 + jj][l16];
                A1u.us[jj]     = Vc[rb][dt][32 + sub * 4 + jj][l16];
                A1u.us[jj + 4] = Vc[rb][dt][48 + sub * 4 + jj][l16];
            }
            o[dt] = __builtin_amdgcn_mfma_f32_16x16x32_f16(A0u.h, pB0, o[dt], 0, 0, 0);
            o[dt] = __builtin_amdgcn_mfma_f32_16x16x32_f16(A1u.h, pB1, o[dt], 0, 0, 0);
        }

        if (kvt < 31) STAGE_WRITE(rb ^ 1)
        __syncthreads();
    }

    // ---- epilogue: out^T = fc @ (Y^T + C^T/l), all in-register
    float inv_l = 1.0f / l_r;
    half8 Bo[4];
#pragma unroll
    for (int kt = 0; kt < 4; ++kt) {
        half8 v;
#pragma unroll
        for (int jh = 0; jh < 2; ++jh) {
            float4 yv = *(const float4*)&Yb[qrow * 128 + kt * 32 + jh * 16 + sub * 4];
            f32x4 oc = o[kt * 2 + jh];
            v[jh * 4 + 0] = (_Float16)(yv.x + oc[0] * inv_l);
            v[jh * 4 + 1] = (_Float16)(yv.y + oc[1] * inv_l);
            v[jh * 4 + 2] = (_Float16)(yv.z + oc[2] * inv_l);
            v[jh * 4 + 3] = (_Float16)(yv.w + oc[3] * inv_l);
        }
        Bo[kt] = v;
    }
#pragma unroll
    for (int jt = 0; jt < 4; ++jt) {
        f32x4 acc = {0.f, 0.f, 0.f, 0.f};
#pragma unroll
        for (int kt = 0; kt < 4; ++kt) {
            float4 w0 = *(const float4*)&fc_w[(jt * 16 + l16) * 128 + kt * 32 + sub * 4];
            float4 w1 = *(const float4*)&fc_w[(jt * 16 + l16) * 128 + kt * 32 + 16 + sub * 4];
            half8 fa;
            fa[0] = (_Float16)w0.x; fa[1] = (_Float16)w0.y;
            fa[2] = (_Float16)w0.z; fa[3] = (_Float16)w0.w;
            fa[4] = (_Float16)w1.x; fa[5] = (_Float16)w1.y;
            fa[6] = (_Float16)w1.z; fa[7] = (_Float16)w1.w;
            acc = __builtin_amdgcn_mfma_f32_16x16x32_f16(fa, Bo[kt], acc, 0, 0, 0);
        }
        float4 bb = *(const float4*)&fc_b[jt * 16 + sub * 4];
        float4 r;
        r.x = acc[0] + bb.x; r.y = acc[1] + bb.y;
        r.z = acc[2] + bb.z; r.w = acc[3] + bb.w;
        *(float4*)&out[((size_t)b * 2048 + qrow) * 64 + jt * 16 + sub * 4] = r;
    }
#undef STAGE_LOAD
#undef STAGE_WRITE
}

// ---------------------------------------------------------------------------
extern "C" void kernel_launch(void* const* d_in, const int* in_sizes, int n_in,
                              void* d_out, int out_size, void* d_ws, size_t ws_size,
                              hipStream_t stream) {
    const float* x   = (const float*)d_in[0];
    const float* h0  = (const float*)d_in[1];
    const float* c0  = (const float*)d_in[2];
    const float* Wih = (const float*)d_in[3];
    const float* Whh = (const float*)d_in[4];
    const float* bih = (const float*)d_in[5];
    const float* bhh = (const float*)d_in[6];
    const float* fcw = (const float*)d_in[7];
    const float* fcb = (const float*)d_in[8];
    (void)in_sizes; (void)n_in; (void)out_size; (void)ws_size;

    float* out = (float*)d_out;
    float* hn = out + (size_t)8 * 2048 * 64;
    float* cn = hn + 1024;

    float* xp2 = (float*)d_ws;                       // 8*2048*512 fp32 = 32 MB
    float* ys  = xp2 + (size_t)8 * 2048 * 512;       // 8*2048*128 fp32 = 8 MB

    xproj_kernel<<<2048, 256, 0, stream>>>(x, Wih, bih, bhh, xp2);
    lstm_kernel<<<8, 512, 0, stream>>>(xp2, Whh, h0, c0, ys, hn, cn);
    dim3 grid_attn(32, 8);
    attn_kernel<<<grid_attn, 256, 0, stream>>>(ys, fcw, fcb, out);
}

// Round 9
// 1045.221 us; speedup vs baseline: 3.1550x; 1.0034x over previous
//
#include <hip/hip_runtime.h>
#include <cstddef>
#include <cstdint>

// Problem: B=8, S=2048, IN=64, H=128, OUT=64. All fp32.
// out = [8,2048,64] (1,048,576) ++ hn [1,8,128] (1024) ++ cn [1,8,128] (1024)

using short8 = __attribute__((ext_vector_type(8))) short;
using half8  = __attribute__((ext_vector_type(8))) _Float16;
using f32x4  = __attribute__((ext_vector_type(4))) float;

#define LOG2E  1.4426950408889634f
#define LOG2E2 2.8853900817779268f

__device__ __forceinline__ unsigned short f2h(float f) {
    return __builtin_bit_cast(unsigned short, (_Float16)f);
}

union H8U { half8 h; uint4 u; ushort us[8]; };
__device__ __forceinline__ half8 h8_from(uint2 a, uint2 b) {
    H8U x; x.u = make_uint4(a.x, a.y, b.x, b.y); return x.h;
}

// ---------------------------------------------------------------------------
// Kernel 1: x_proj, interleaved + pre-scaled by log2(e):
//   xp2[((b*2048+s)*128 + cell)*4 + part] = log2e*(x@W_ih + b_ih + b_hh)
// ---------------------------------------------------------------------------
__global__ __launch_bounds__(256) void xproj_kernel(
    const float* __restrict__ x, const float* __restrict__ W_ih,
    const float* __restrict__ b_ih, const float* __restrict__ b_hh,
    float* __restrict__ xp2)
{
    __shared__ __align__(16) float xs[8][64];
    const int t = threadIdx.x;
    const long row0 = (long)blockIdx.x * 8;

    if (t < 128) {
        int r = t >> 4, c4 = (t & 15) * 4;
        *(float4*)&xs[r][c4] = *(const float4*)&x[(row0 + r) * 64 + c4];
    }
    __syncthreads();

    const int g0 = t, g1 = t + 256;
    float acc0[8], acc1[8];
#pragma unroll
    for (int r = 0; r < 8; ++r) { acc0[r] = 0.f; acc1[r] = 0.f; }

#pragma unroll
    for (int c = 0; c < 16; ++c) {
        float4 w0 = *(const float4*)&W_ih[g0 * 64 + c * 4];
        float4 w1 = *(const float4*)&W_ih[g1 * 64 + c * 4];
#pragma unroll
        for (int r = 0; r < 8; ++r) {
            float4 xv = *(const float4*)&xs[r][c * 4];
            acc0[r] += w0.x * xv.x + w0.y * xv.y + w0.z * xv.z + w0.w * xv.w;
            acc1[r] += w1.x * xv.x + w1.y * xv.y + w1.z * xv.z + w1.w * xv.w;
        }
    }
    const float bb0 = b_ih[g0] + b_hh[g0];
    const float bb1 = b_ih[g1] + b_hh[g1];
    const int c0i = g0 & 127, p0 = g0 >> 7;
    const int c1i = g1 & 127, p1 = g1 >> 7;
#pragma unroll
    for (int r = 0; r < 8; ++r) {
        xp2[((row0 + r) * 128 + c0i) * 4 + p0] = (acc0[r] + bb0) * LOG2E;
        xp2[((row0 + r) * 128 + c1i) * 4 + p1] = (acc1[r] + bb1) * LOG2E;
    }
}

// ---------------------------------------------------------------------------
// Kernel 2: MFMA LSTM (round-4/7 proven body, 918 us, model-validated).
// ---------------------------------------------------------------------------
__global__ __launch_bounds__(512, 2) void lstm_kernel(
    const float* __restrict__ xp2, const float* __restrict__ W_hh,
    const float* __restrict__ h0, const float* __restrict__ c0,
    float* __restrict__ ys, float* __restrict__ hn, float* __restrict__ cn)
{
    const int b    = blockIdx.x;
    const int t    = threadIdx.x;
    const int w    = t >> 6;
    const int lane = t & 63;
    const int l16  = lane & 15;
    const int sub  = lane >> 4;

    __shared__ __align__(16) _Float16 afrag[2][4][8][8];

    half8 Bf[4][4];
#pragma unroll
    for (int gi = 0; gi < 4; ++gi) {
        const int gate = (w + 8 * gi) * 16 + l16;
#pragma unroll
        for (int kt = 0; kt < 4; ++kt) {
            half8 v;
#pragma unroll
            for (int j = 0; j < 8; ++j) {
                int k = kt * 32 + (j >> 2) * 16 + sub * 4 + (j & 3);
                v[j] = (_Float16)(W_hh[gate * 128 + k] * LOG2E);
            }
            Bf[gi][kt] = v;
        }
    }

    const int cell = w * 16 + l16;
    float c_reg = 0.f, h_last = 0.f;

    const int wkt   = cell >> 5;
    const int wkl   = cell & 31;
    const int wslot = ((wkl >> 2) & 3) * 2;
    const int welem = (wkl >> 4) * 4 + (wkl & 3);
    _Float16* whi = &afrag[0][wkt][wslot + 0][welem];
    _Float16* wlo = &afrag[0][wkt][wslot + 1][welem];

    const _Float16* aread = &afrag[0][0][sub * 2 + (l16 & 1)][0];

    if (lane < 16) {
        c_reg  = c0[b * 128 + cell];
        h_last = h0[b * 128 + cell];
        _Float16 hh = (_Float16)h_last;
        whi[0] = hh;
        wlo[0] = (_Float16)(h_last - (float)hh);
    }
    __syncthreads();

    const float* xpl = xp2 + (size_t)b * 2048 * 512 + cell * 4;
    float*       yp  = ys  + (size_t)b * 2048 * 128 + cell;

    half8 A[4];
#pragma unroll
    for (int kt = 0; kt < 4; ++kt)
#pragma unroll
        for (int j = 0; j < 8; ++j) A[kt][j] = (_Float16)0.f;

    float4 xqA = *(const float4*)xpl;
    float4 xqB = *(const float4*)(xpl + 512);
    const float* pA = xpl + 1024;
    const float* pB = xpl + 1536;

#define LSTM_STEP(RB, WB, XQV, PP)                                            \
    {                                                                         \
        if (l16 < 2) {                                                        \
            A[0] = *(const half8*)(aread + (RB) * 256 + 0);                   \
            A[1] = *(const half8*)(aread + (RB) * 256 + 64);                  \
            A[2] = *(const half8*)(aread + (RB) * 256 + 128);                 \
            A[3] = *(const half8*)(aread + (RB) * 256 + 192);                 \
        }                                                                     \
        float4 xnew = *(const float4*)(PP); (PP) += 1024;                     \
        f32x4 ac0 = {0.f, 0.f, 0.f, 0.f};                                     \
        f32x4 ac1 = ac0, ac2 = ac0, ac3 = ac0;                                \
        _Pragma("unroll")                                                     \
        for (int kt = 0; kt < 4; ++kt) {                                      \
            ac0 = __builtin_amdgcn_mfma_f32_16x16x32_f16(A[kt], Bf[0][kt], ac0, 0, 0, 0); \
            ac1 = __builtin_amdgcn_mfma_f32_16x16x32_f16(A[kt], Bf[1][kt], ac1, 0, 0, 0); \
            ac2 = __builtin_amdgcn_mfma_f32_16x16x32_f16(A[kt], Bf[2][kt], ac2, 0, 0, 0); \
            ac3 = __builtin_amdgcn_mfma_f32_16x16x32_f16(A[kt], Bf[3][kt], ac3, 0, 0, 0); \
        }                                                                     \
        if (lane < 16) {                                                      \
            float gi_ = ac0[0] + ac0[1] + (XQV).x;                            \
            float gf_ = ac1[0] + ac1[1] + (XQV).y;                            \
            float gg_ = ac2[0] + ac2[1] + (XQV).z;                            \
            float go_ = ac3[0] + ac3[1] + (XQV).w;                            \
            float i_ = __builtin_amdgcn_rcpf(1.f + __builtin_amdgcn_exp2f(-gi_)); \
            float f_ = __builtin_amdgcn_rcpf(1.f + __builtin_amdgcn_exp2f(-gf_)); \
            float o_ = __builtin_amdgcn_rcpf(1.f + __builtin_amdgcn_exp2f(-go_)); \
            float g_ = 1.f - 2.f * __builtin_amdgcn_rcpf(1.f + __builtin_amdgcn_exp2f(gg_ + gg_)); \
            c_reg = f_ * c_reg + i_ * g_;                                     \
            float tc_ = 1.f - 2.f * __builtin_amdgcn_rcpf(1.f + __builtin_amdgcn_exp2f(c_reg * LOG2E2)); \
            float h = o_ * tc_;                                               \
            h_last = h;                                                       \
            *yp = h;                                                          \
            _Float16 hh = (_Float16)h;                                        \
            whi[(WB) * 256] = hh;                                             \
            wlo[(WB) * 256] = (_Float16)(h - (float)hh);                      \
        }                                                                     \
        yp += 128;                                                            \
        (XQV) = xnew;                                                         \
        __builtin_amdgcn_sched_barrier(0);                                    \
        asm volatile("s_waitcnt lgkmcnt(0)" ::: "memory");                    \
        __builtin_amdgcn_s_barrier();                                         \
        __builtin_amdgcn_sched_barrier(0);                                    \
    }

    for (int s = 0; s < 2048; s += 2) {
        LSTM_STEP(0, 1, xqA, pA)
        LSTM_STEP(1, 0, xqB, pB)
    }
#undef LSTM_STEP

    if (lane < 16) {
        hn[b * 128 + cell] = h_last;
        cn[b * 128 + cell] = c_reg;
    }
}

// ---------------------------------------------------------------------------
// Kernel 3: MFMA flash attention, round-7 PASSING structure (all-C, scalar
// u16 PV gather). ONE change: Vc plane inner dim padded 16 -> 20 ushorts so
// the gather's bank pattern becomes (8*sub + 10*jj + l16/2) mod 32 -> the 4
// subs land 8 banks apart => <=2-way (free) instead of 8-way. Values are
// bit-identical to round 7. tr_read abandoned (2 strikes, rounds 6 & 8:
// deterministic identical miscompute under 2 different waitcnt schemes).
// ---------------------------------------------------------------------------
__global__ __launch_bounds__(256) void attn_kernel(
    const float* __restrict__ ys, const float* __restrict__ fc_w,
    const float* __restrict__ fc_b, float* __restrict__ out)
{
    __shared__ __align__(16) ushort Ks[2][64 * 128];   // 32 KB, swizzled
    __shared__ __align__(16) ushort Vc[2][8][64][20];  // 40 KB, padded planes
    __shared__ __align__(16) ushort Pl[4][16][68];     // 8.5 KB, per-wave P

    const int b = blockIdx.y, qt = blockIdx.x;
    const int t = threadIdx.x;
    const int w = t >> 6, lane = t & 63, l16 = lane & 15, sub = lane >> 4;
    const float* Yb = ys + (size_t)b * 2048 * 128;

    // ---- Q fragments (fp16, pre-scaled by log2e). B-side: n=q=l16, k=d.
    const int qrow = qt * 64 + w * 16 + l16;
    half8 Qf[4];
#pragma unroll
    for (int kt = 0; kt < 4; ++kt) {
        float4 a0 = *(const float4*)&Yb[qrow * 128 + kt * 32 + sub * 4];
        float4 a1 = *(const float4*)&Yb[qrow * 128 + kt * 32 + 16 + sub * 4];
        half8 v;
        v[0] = (_Float16)(a0.x * LOG2E); v[1] = (_Float16)(a0.y * LOG2E);
        v[2] = (_Float16)(a0.z * LOG2E); v[3] = (_Float16)(a0.w * LOG2E);
        v[4] = (_Float16)(a1.x * LOG2E); v[5] = (_Float16)(a1.y * LOG2E);
        v[6] = (_Float16)(a1.z * LOG2E); v[7] = (_Float16)(a1.w * LOG2E);
        Qf[kt] = v;
    }

    float4 st[8];   // stage registers (load early, LDS-write late)
#define STAGE_LOAD(KVT)                                                      \
    {                                                                        \
        const float* src = Yb + (size_t)(KVT) * 64 * 128;                    \
        _Pragma("unroll")                                                    \
        for (int p = 0; p < 8; ++p) {                                        \
            int idx = p * 256 + t;                                           \
            st[p] = *(const float4*)&src[idx * 4];                           \
        }                                                                    \
    }
#define STAGE_WRITE(BUF)                                                     \
    {                                                                        \
        char* kbase = (char*)&Ks[BUF][0];                                    \
        _Pragma("unroll")                                                    \
        for (int p = 0; p < 8; ++p) {                                        \
            int idx = p * 256 + t;                                           \
            int kv = idx >> 5, d4 = (idx & 31) * 4;                          \
            ushort4 hv;                                                      \
            hv.x = f2h(st[p].x); hv.y = f2h(st[p].y);                        \
            hv.z = f2h(st[p].z); hv.w = f2h(st[p].w);                        \
            uint koff = (uint)((kv * 256 + d4 * 2) ^ ((kv & 7) << 4));       \
            *(ushort4*)(kbase + koff) = hv;                                  \
            *(ushort4*)&Vc[BUF][d4 >> 4][kv][d4 & 15] = hv;                  \
        }                                                                    \
    }

    // prologue: stage tile 0
    STAGE_LOAD(0)
    STAGE_WRITE(0)
    __syncthreads();

    float m_r = -1e30f, l_r = 0.f;
    f32x4 o[8];
#pragma unroll
    for (int dt = 0; dt < 8; ++dt) o[dt] = (f32x4){0.f, 0.f, 0.f, 0.f};

    for (int kvt = 0; kvt < 32; ++kvt) {
        const int rb = kvt & 1;
        if (kvt < 31) STAGE_LOAD(kvt + 1)

        // ---- QK: S^T[kv = rt*16+sub*4+reg][q = l16]
        const char* kp = (const char*)&Ks[rb][0];
        f32x4 s[4];
#pragma unroll
        for (int rt = 0; rt < 4; ++rt) {
            f32x4 sa = {0.f, 0.f, 0.f, 0.f};
            int row = rt * 16 + l16;
            int sw  = (row & 7) << 4;
#pragma unroll
            for (int kt = 0; kt < 4; ++kt) {
                int base0 = row * 256 + (kt * 32 + sub * 4) * 2;
                uint2 q0 = *(const uint2*)(kp + (base0 ^ sw));
                uint2 q1 = *(const uint2*)(kp + ((base0 + 32) ^ sw));
                sa = __builtin_amdgcn_mfma_f32_16x16x32_f16(h8_from(q0, q1), Qf[kt], sa, 0, 0, 0);
            }
            s[rt] = sa;
        }

        // ---- online softmax; butterfly over the 4 sub-lanes (xor 16/32)
        float pm = s[0][0];
#pragma unroll
        for (int rt = 0; rt < 4; ++rt)
#pragma unroll
            for (int r = 0; r < 4; ++r) pm = fmaxf(pm, s[rt][r]);
        pm = fmaxf(pm, __shfl_xor(pm, 16));
        pm = fmaxf(pm, __shfl_xor(pm, 32));
        float mnew = fmaxf(m_r, pm);
        float sc = __builtin_amdgcn_exp2f(m_r - mnew);
        m_r = mnew;
        float psum = 0.f;
        float pv[4][4];
#pragma unroll
        for (int rt = 0; rt < 4; ++rt)
#pragma unroll
            for (int r = 0; r < 4; ++r) {
                pv[rt][r] = __builtin_amdgcn_exp2f(s[rt][r] - mnew);
                psum += pv[rt][r];
            }
        psum += __shfl_xor(psum, 16);
        psum += __shfl_xor(psum, 32);
        l_r = l_r * sc + psum;
#pragma unroll
        for (int dt = 0; dt < 8; ++dt) {
            o[dt][0] *= sc; o[dt][1] *= sc; o[dt][2] *= sc; o[dt][3] *= sc;
        }

        // ---- P[q=l16][kv] exchange via per-wave LDS (plain C, same wave)
#pragma unroll
        for (int rt = 0; rt < 4; ++rt) {
            uint lo = (uint)f2h(pv[rt][0]) | ((uint)f2h(pv[rt][1]) << 16);
            uint hi = (uint)f2h(pv[rt][2]) | ((uint)f2h(pv[rt][3]) << 16);
            *(uint2*)&Pl[w][l16][rt * 16 + sub * 4] = make_uint2(lo, hi);
        }
        uint2 pf0 = *(const uint2*)&Pl[w][l16][0  + sub * 4];
        uint2 pf1 = *(const uint2*)&Pl[w][l16][16 + sub * 4];
        uint2 pf2 = *(const uint2*)&Pl[w][l16][32 + sub * 4];
        uint2 pf3 = *(const uint2*)&Pl[w][l16][48 + sub * 4];
        half8 pB0 = h8_from(pf0, pf1);
        half8 pB1 = h8_from(pf2, pf3);

        // ---- PV: context^T += V^T @ P; A gathered as scalar u16 reads
        //      (padded stride 20 -> <=2-way banks)
#pragma unroll
        for (int dt = 0; dt < 8; ++dt) {
            H8U A0u, A1u;
#pragma unroll
            for (int jj = 0; jj < 4; ++jj) {
                A0u.us[jj]     = Vc[rb][dt][     sub * 4 + jj][l16];
                A0u.us[jj + 4] = Vc[rb][dt][16 + sub * 4 + jj][l16];
                A1u.us[jj]     = Vc[rb][dt][32 + sub * 4 + jj][l16];
                A1u.us[jj + 4] = Vc[rb][dt][48 + sub * 4 + jj][l16];
            }
            o[dt] = __builtin_amdgcn_mfma_f32_16x16x32_f16(A0u.h, pB0, o[dt], 0, 0, 0);
            o[dt] = __builtin_amdgcn_mfma_f32_16x16x32_f16(A1u.h, pB1, o[dt], 0, 0, 0);
        }

        if (kvt < 31) STAGE_WRITE(rb ^ 1)
        __syncthreads();
    }

    // ---- epilogue: out^T = fc @ (Y^T + C^T/l), all in-register
    float inv_l = 1.0f / l_r;
    half8 Bo[4];
#pragma unroll
    for (int kt = 0; kt < 4; ++kt) {
        half8 v;
#pragma unroll
        for (int jh = 0; jh < 2; ++jh) {
            float4 yv = *(const float4*)&Yb[qrow * 128 + kt * 32 + jh * 16 + sub * 4];
            f32x4 oc = o[kt * 2 + jh];
            v[jh * 4 + 0] = (_Float16)(yv.x + oc[0] * inv_l);
            v[jh * 4 + 1] = (_Float16)(yv.y + oc[1] * inv_l);
            v[jh * 4 + 2] = (_Float16)(yv.z + oc[2] * inv_l);
            v[jh * 4 + 3] = (_Float16)(yv.w + oc[3] * inv_l);
        }
        Bo[kt] = v;
    }
#pragma unroll
    for (int jt = 0; jt < 4; ++jt) {
        f32x4 acc = {0.f, 0.f, 0.f, 0.f};
#pragma unroll
        for (int kt = 0; kt < 4; ++kt) {
            float4 w0 = *(const float4*)&fc_w[(jt * 16 + l16) * 128 + kt * 32 + sub * 4];
            float4 w1 = *(const float4*)&fc_w[(jt * 16 + l16) * 128 + kt * 32 + 16 + sub * 4];
            half8 fa;
            fa[0] = (_Float16)w0.x; fa[1] = (_Float16)w0.y;
            fa[2] = (_Float16)w0.z; fa[3] = (_Float16)w0.w;
            fa[4] = (_Float16)w1.x; fa[5] = (_Float16)w1.y;
            fa[6] = (_Float16)w1.z; fa[7] = (_Float16)w1.w;
            acc = __builtin_amdgcn_mfma_f32_16x16x32_f16(fa, Bo[kt], acc, 0, 0, 0);
        }
        float4 bb = *(const float4*)&fc_b[jt * 16 + sub * 4];
        float4 r;
        r.x = acc[0] + bb.x; r.y = acc[1] + bb.y;
        r.z = acc[2] + bb.z; r.w = acc[3] + bb.w;
        *(float4*)&out[((size_t)b * 2048 + qrow) * 64 + jt * 16 + sub * 4] = r;
    }
#undef STAGE_LOAD
#undef STAGE_WRITE
}

// ---------------------------------------------------------------------------
extern "C" void kernel_launch(void* const* d_in, const int* in_sizes, int n_in,
                              void* d_out, int out_size, void* d_ws, size_t ws_size,
                              hipStream_t stream) {
    const float* x   = (const float*)d_in[0];
    const float* h0  = (const float*)d_in[1];
    const float* c0  = (const float*)d_in[2];
    const float* Wih = (const float*)d_in[3];
    const float* Whh = (const float*)d_in[4];
    const float* bih = (const float*)d_in[5];
    const float* bhh = (const float*)d_in[6];
    const float* fcw = (const float*)d_in[7];
    const float* fcb = (const float*)d_in[8];
    (void)in_sizes; (void)n_in; (void)out_size; (void)ws_size;

    float* out = (float*)d_out;
    float* hn = out + (size_t)8 * 2048 * 64;
    float* cn = hn + 1024;

    float* xp2 = (float*)d_ws;                       // 8*2048*512 fp32 = 32 MB
    float* ys  = xp2 + (size_t)8 * 2048 * 512;       // 8*2048*128 fp32 = 8 MB

    xproj_kernel<<<2048, 256, 0, stream>>>(x, Wih, bih, bhh, xp2);
    lstm_kernel<<<8, 512, 0, stream>>>(xp2, Whh, h0, c0, ys, hn, cn);
    dim3 grid_attn(32, 8);
    attn_kernel<<<grid_attn, 256, 0, stream>>>(ys, fcw, fcb, out);
}